// Round 1
// baseline (257.977 us; speedup 1.0000x reference)
//
#include <hip/hip_runtime.h>
#include <hip/hip_bf16.h>
#include <cstdint>
#include <cstddef>

#define N_PATH 14
#define NEG_SLOPE 0.2f

__device__ __forceinline__ float lrelu(float v) { return v > 0.f ? v : NEG_SLOPE * v; }

// ------------------------------------------------------------------
// Frontier building.
// counters: cnt[0]=cntB, cnt[1]=cntC, cnt[2]=cntE1, cnt[3]=cntE2
// ------------------------------------------------------------------
__global__ void k_build2(const int* __restrict__ esrc, const int* __restrict__ edst,
                         int E, int Nn,
                         int* __restrict__ mapB, int* __restrict__ listB,
                         int* __restrict__ cnt,
                         int* __restrict__ e2srcRaw, int* __restrict__ e2dstA,
                         int capB, int capE2)
{
    int e = blockIdx.x * blockDim.x + threadIdx.x;
    int ET = E + Nn;
    if (e >= ET) return;
    int s, d;
    if (e < E) { s = esrc[e]; d = edst[e]; } else { s = e - E; d = s; }
    if (d >= N_PATH) return;
    int slot = atomicAdd(&cnt[3], 1);
    if (slot < capE2) { e2srcRaw[slot] = s; e2dstA[slot] = d; }
    int old = atomicCAS(&mapB[s], -1, -2);
    if (old == -1) {
        int idx = atomicAdd(&cnt[0], 1);
        if (idx < capB) listB[idx] = s;
        mapB[s] = idx;
    }
}

__global__ void k_build1(const int* __restrict__ esrc, const int* __restrict__ edst,
                         int E, int Nn,
                         const int* __restrict__ mapB,
                         int* __restrict__ mapC, int* __restrict__ listC,
                         int* __restrict__ cnt,
                         int* __restrict__ e1srcRaw, int* __restrict__ e1dstB,
                         int capB, int capC, int capE1)
{
    int e = blockIdx.x * blockDim.x + threadIdx.x;
    int ET = E + Nn;
    if (e >= ET) return;
    int s, d;
    if (e < E) { s = esrc[e]; d = edst[e]; } else { s = e - E; d = s; }
    int b = mapB[d];
    if (b < 0 || b >= capB) return;
    int slot = atomicAdd(&cnt[2], 1);
    if (slot < capE1) { e1srcRaw[slot] = s; e1dstB[slot] = b; }
    int old = atomicCAS(&mapC[s], -1, -2);
    if (old == -1) {
        int idx = atomicAdd(&cnt[1], 1);
        if (idx < capC) listC[idx] = s;
        mapC[s] = idx;
    }
}

__global__ void k_remap(const int* __restrict__ mapB, const int* __restrict__ mapC,
                        const int* __restrict__ cnt,
                        const int* __restrict__ e1srcRaw, int* __restrict__ e1srcC,
                        const int* __restrict__ e2srcRaw, int* __restrict__ e2srcB,
                        const int* __restrict__ e2dstA, int* __restrict__ e2dstB,
                        int capB, int capC, int capE1, int capE2)
{
    int i = blockIdx.x * blockDim.x + threadIdx.x;
    int n1 = cnt[2]; if (n1 > capE1) n1 = capE1;
    int n2 = cnt[3]; if (n2 > capE2) n2 = capE2;
    if (i < n1) {
        int c = mapC[e1srcRaw[i]];
        if (c < 0) c = 0; if (c >= capC) c = capC - 1;
        e1srcC[i] = c;
    }
    if (i < n2) {
        int b = mapB[e2srcRaw[i]];
        if (b < 0) b = 0; if (b >= capB) b = capB - 1;
        e2srcB[i] = b;
        int bd = mapB[e2dstA[i]];
        if (bd < 0) bd = 0; if (bd >= capB) bd = capB - 1;
        e2dstB[i] = bd;
    }
}

// Zero only the rows that will actually be accumulated into.
__global__ void k_zero(float* __restrict__ XL1, float* __restrict__ XR1,
                       float* __restrict__ H1, float* __restrict__ XL2,
                       float* __restrict__ XR2,
                       const int* __restrict__ cnt, int capB, int capC)
{
    int nB = cnt[0]; if (nB > capB) nB = capB;
    int nC = cnt[1]; if (nC > capC) nC = capC;
    size_t tC  = (size_t)nC * 3072;
    size_t tB  = (size_t)nB * 3072;
    size_t tB2 = (size_t)nB * 768;
    size_t total = tC + 2 * tB + 2 * tB2;
    size_t stride = (size_t)gridDim.x * blockDim.x;
    for (size_t i = (size_t)blockIdx.x * blockDim.x + threadIdx.x; i < total; i += stride) {
        size_t j = i;
        if (j < tC)  { XL1[j] = 0.f; continue; } j -= tC;
        if (j < tB)  { XR1[j] = 0.f; continue; } j -= tB;
        if (j < tB)  { H1[j]  = 0.f; continue; } j -= tB;
        if (j < tB2) { XL2[j] = 0.f; continue; } j -= tB2;
        XR2[j] = 0.f;
    }
}

// ------------------------------------------------------------------
// Split-K tiled fp32 GEMM: C[r,n] += sum_k A[g(r),k] * W[k,n]
// tile 64x64, BK=16, 256 threads, atomicAdd accumulation (no bias).
// ------------------------------------------------------------------
__global__ __launch_bounds__(256)
void k_gemm(const float* __restrict__ A, int lda, const int* __restrict__ gather,
            const float* __restrict__ W, int ldw,
            float* __restrict__ C, int ldc,
            const int* __restrict__ cnt, int cntIdx, int capM,
            int K, int splits)
{
    __shared__ float As[16][64];
    __shared__ float Bs[16][64];
    int M = cnt[cntIdx]; if (M > capM) M = capM;
    int m0 = blockIdx.y * 64;
    if (m0 >= M) return;
    int n0 = blockIdx.x * 64;
    int kchunk = K / splits;
    int k0 = blockIdx.z * kchunk;
    int t = threadIdx.x;
    int lm = t & 63, kq = t >> 6;
    int tn = t & 15, tm = t >> 4;
    int arow = m0 + lm;
    int ga;
    if (arow < M) ga = gather ? gather[arow] : arow;
    else          ga = gather ? gather[0]    : 0;
    const float* Ap = A + (size_t)ga * lda;
    float acc[4][4];
    for (int i = 0; i < 4; ++i)
        for (int j = 0; j < 4; ++j) acc[i][j] = 0.f;

    for (int kt = k0; kt < k0 + kchunk; kt += 16) {
        float4 av = *reinterpret_cast<const float4*>(Ap + kt + kq * 4);
        As[kq*4+0][lm] = av.x; As[kq*4+1][lm] = av.y;
        As[kq*4+2][lm] = av.z; As[kq*4+3][lm] = av.w;
        const float* wp = W + (size_t)(kt + kq * 4) * ldw + n0 + lm;
        Bs[kq*4+0][lm] = wp[0];
        Bs[kq*4+1][lm] = wp[(size_t)ldw];
        Bs[kq*4+2][lm] = wp[2*(size_t)ldw];
        Bs[kq*4+3][lm] = wp[3*(size_t)ldw];
        __syncthreads();
        #pragma unroll
        for (int kk = 0; kk < 16; ++kk) {
            float4 a4 = *reinterpret_cast<const float4*>(&As[kk][tm*4]);
            float4 b4 = *reinterpret_cast<const float4*>(&Bs[kk][tn*4]);
            float aa[4] = {a4.x, a4.y, a4.z, a4.w};
            float bb[4] = {b4.x, b4.y, b4.z, b4.w};
            #pragma unroll
            for (int i = 0; i < 4; ++i)
                #pragma unroll
                for (int j = 0; j < 4; ++j)
                    acc[i][j] = fmaf(aa[i], bb[j], acc[i][j]);
        }
        __syncthreads();
    }
    #pragma unroll
    for (int i = 0; i < 4; ++i) {
        int r = m0 + tm * 4 + i;
        if (r < M) {
            float* crow = C + (size_t)r * ldc + n0 + tn * 4;
            #pragma unroll
            for (int j = 0; j < 4; ++j) atomicAdd(&crow[j], acc[i][j]);
        }
    }
}

// ------------------------------------------------------------------
// Layer-1 edge kernels (H=4 heads, 768 ch/head). One wave per edge.
// ------------------------------------------------------------------
__global__ void k_att1(const float* __restrict__ XL1, const float* __restrict__ XR1,
                       const float* __restrict__ att1,
                       const float* __restrict__ bl1, const float* __restrict__ br1,
                       const int* __restrict__ e1srcC, const int* __restrict__ e1dstB,
                       float* __restrict__ e1exp, float* __restrict__ den1,
                       const int* __restrict__ cnt, int capE1)
{
    int nE = cnt[2]; if (nE > capE1) nE = capE1;
    int lane = threadIdx.x & 63;
    int wid = (blockIdx.x * blockDim.x + threadIdx.x) >> 6;
    int nW  = (gridDim.x * blockDim.x) >> 6;
    for (int i = wid; i < nE; i += nW) {
        int c = e1srcC[i], b = e1dstB[i];
        const float* xl = XL1 + (size_t)c * 3072;
        const float* xr = XR1 + (size_t)b * 3072;
        float part[4] = {0.f, 0.f, 0.f, 0.f};
        #pragma unroll
        for (int h = 0; h < 4; ++h) {
            int base = h * 768;
            #pragma unroll
            for (int j = 0; j < 12; ++j) {
                int k = base + j * 64 + lane;
                float s = xl[k] + xr[k] + bl1[k] + br1[k];
                s = lrelu(s);
                part[h] = fmaf(att1[k], s, part[h]);
            }
        }
        #pragma unroll
        for (int h = 0; h < 4; ++h) {
            float v = part[h];
            for (int off = 32; off > 0; off >>= 1) v += __shfl_xor(v, off);
            if (lane == 0) {
                float ex = expf(v);
                e1exp[i * 4 + h] = ex;
                atomicAdd(&den1[b * 4 + h], ex);
            }
        }
    }
}

__global__ void k_agg1(const float* __restrict__ XL1,
                       const float* __restrict__ e1exp, const float* __restrict__ den1,
                       const int* __restrict__ e1srcC, const int* __restrict__ e1dstB,
                       float* __restrict__ H1,
                       const int* __restrict__ cnt, int capE1)
{
    int nE = cnt[2]; if (nE > capE1) nE = capE1;
    int lane = threadIdx.x & 63;
    int wid = (blockIdx.x * blockDim.x + threadIdx.x) >> 6;
    int nW  = (gridDim.x * blockDim.x) >> 6;
    for (int i = wid; i < nE; i += nW) {
        int c = e1srcC[i], b = e1dstB[i];
        const float* xl = XL1 + (size_t)c * 3072;
        float* hb = H1 + (size_t)b * 3072;
        float al[4];
        #pragma unroll
        for (int h = 0; h < 4; ++h)
            al[h] = e1exp[i * 4 + h] / (den1[b * 4 + h] + 1e-16f);
        #pragma unroll
        for (int h = 0; h < 4; ++h) {
            int base = h * 768;
            #pragma unroll
            for (int j = 0; j < 12; ++j) {
                int k = base + j * 64 + lane;
                atomicAdd(&hb[k], al[h] * xl[k]);
            }
        }
    }
}

// h = relu(agg + bl1 + bias1)  (bl1 folded here since sum(alpha)=1)
__global__ void k_hrelu(float* __restrict__ H1,
                        const float* __restrict__ bl1, const float* __restrict__ bias1,
                        const int* __restrict__ cnt, int capB)
{
    int nB = cnt[0]; if (nB > capB) nB = capB;
    size_t total = (size_t)nB * 3072;
    size_t stride = (size_t)gridDim.x * blockDim.x;
    for (size_t i = (size_t)blockIdx.x * blockDim.x + threadIdx.x; i < total; i += stride) {
        int col = (int)(i % 3072);
        float v = H1[i] + bl1[col] + bias1[col];
        H1[i] = v > 0.f ? v : 0.f;
    }
}

// ------------------------------------------------------------------
// Layer-2 edge kernels (H=1, 768 ch). One wave per edge.
// ------------------------------------------------------------------
__global__ void k_att2(const float* __restrict__ XL2, const float* __restrict__ XR2,
                       const float* __restrict__ att2,
                       const float* __restrict__ bl2, const float* __restrict__ br2,
                       const int* __restrict__ e2srcB, const int* __restrict__ e2dstB,
                       const int* __restrict__ e2dstA,
                       float* __restrict__ e2exp, float* __restrict__ den2,
                       const int* __restrict__ cnt, int capE2)
{
    int nE = cnt[3]; if (nE > capE2) nE = capE2;
    int lane = threadIdx.x & 63;
    int wid = (blockIdx.x * blockDim.x + threadIdx.x) >> 6;
    int nW  = (gridDim.x * blockDim.x) >> 6;
    for (int i = wid; i < nE; i += nW) {
        int bs = e2srcB[i], bd = e2dstB[i], a = e2dstA[i];
        const float* xl = XL2 + (size_t)bs * 768;
        const float* xr = XR2 + (size_t)bd * 768;
        float part = 0.f;
        #pragma unroll
        for (int j = 0; j < 12; ++j) {
            int k = j * 64 + lane;
            float s = xl[k] + xr[k] + bl2[k] + br2[k];
            s = lrelu(s);
            part = fmaf(att2[k], s, part);
        }
        for (int off = 32; off > 0; off >>= 1) part += __shfl_xor(part, off);
        if (lane == 0) {
            float ex = expf(part);
            e2exp[i] = ex;
            atomicAdd(&den2[a], ex);
        }
    }
}

__global__ void k_agg2(const float* __restrict__ XL2,
                       const float* __restrict__ e2exp, const float* __restrict__ den2,
                       const int* __restrict__ e2srcB, const int* __restrict__ e2dstA,
                       float* __restrict__ out2acc,
                       const int* __restrict__ cnt, int capE2)
{
    int nE = cnt[3]; if (nE > capE2) nE = capE2;
    int lane = threadIdx.x & 63;
    int wid = (blockIdx.x * blockDim.x + threadIdx.x) >> 6;
    int nW  = (gridDim.x * blockDim.x) >> 6;
    for (int i = wid; i < nE; i += nW) {
        int bs = e2srcB[i], a = e2dstA[i];
        const float* xl = XL2 + (size_t)bs * 768;
        float al = e2exp[i] / (den2[a] + 1e-16f);
        #pragma unroll
        for (int j = 0; j < 12; ++j) {
            int k = j * 64 + lane;
            atomicAdd(&out2acc[a * 768 + k], al * xl[k]);
        }
    }
}

// out = out2acc + bl2 + bias2   (bl2 folded: sum(alpha)=1; H=1 so mean is identity)
__global__ void k_out(const float* __restrict__ out2acc,
                      const float* __restrict__ bl2, const float* __restrict__ bias2,
                      float* __restrict__ out)
{
    int i = blockIdx.x * blockDim.x + threadIdx.x;
    if (i < N_PATH * 768) {
        int col = i % 768;
        out[i] = out2acc[i] + bl2[col] + bias2[col];
    }
}

// ------------------------------------------------------------------
// Host side
// ------------------------------------------------------------------
struct WsLayout {
    size_t mapB, mapC, zeroBase, zeroBytes;
    size_t cntOff, den1, den2, out2acc;
    size_t listB, listC;
    size_t e1srcRaw, e1dstB, e1srcC;
    size_t e2srcRaw, e2dstA, e2srcB, e2dstB;
    size_t e1exp, e2exp;
    size_t XL1, XR1, H1, XL2, XR2;
    size_t total;
};

static WsLayout makeLayout(int Nn, int cB, int cC, int cE1, int cE2)
{
    WsLayout L{};
    size_t off = 0;
    auto take = [&](size_t bytes) { size_t o = (off + 255) & ~(size_t)255; off = o + bytes; return o; };
    L.mapB = take((size_t)2 * Nn * 4);
    L.mapC = L.mapB + (size_t)Nn * 4;
    size_t zb = (size_t)(16 + 4 * cB + 16 + N_PATH * 768) * 4;
    L.zeroBase = take(zb); L.zeroBytes = zb;
    L.cntOff  = L.zeroBase;
    L.den1    = L.zeroBase + 16 * 4;
    L.den2    = L.den1 + (size_t)4 * cB * 4;
    L.out2acc = L.den2 + 16 * 4;
    L.listB = take((size_t)cB * 4);
    L.listC = take((size_t)cC * 4);
    L.e1srcRaw = take((size_t)cE1 * 4);
    L.e1dstB   = take((size_t)cE1 * 4);
    L.e1srcC   = take((size_t)cE1 * 4);
    L.e2srcRaw = take((size_t)cE2 * 4);
    L.e2dstA   = take((size_t)cE2 * 4);
    L.e2srcB   = take((size_t)cE2 * 4);
    L.e2dstB   = take((size_t)cE2 * 4);
    L.e1exp = take((size_t)cE1 * 4 * 4);
    L.e2exp = take((size_t)cE2 * 4);
    L.XL1 = take((size_t)cC * 3072 * 4);
    L.XR1 = take((size_t)cB * 3072 * 4);
    L.H1  = take((size_t)cB * 3072 * 4);
    L.XL2 = take((size_t)cB * 768 * 4);
    L.XR2 = take((size_t)cB * 768 * 4);
    L.total = off;
    return L;
}

extern "C" void kernel_launch(void* const* d_in, const int* in_sizes, int n_in,
                              void* d_out, int out_size, void* d_ws, size_t ws_size,
                              hipStream_t stream)
{
    const float* x     = (const float*)d_in[0];
    const int*   ei    = (const int*)  d_in[1];
    const float* Wl1   = (const float*)d_in[2];
    const float* bl1   = (const float*)d_in[3];
    const float* Wr1   = (const float*)d_in[4];
    const float* br1   = (const float*)d_in[5];
    const float* att1  = (const float*)d_in[6];
    const float* bias1 = (const float*)d_in[7];
    const float* Wl2   = (const float*)d_in[8];
    const float* bl2   = (const float*)d_in[9];
    const float* Wr2   = (const float*)d_in[10];
    const float* br2   = (const float*)d_in[11];
    const float* att2  = (const float*)d_in[12];
    const float* bias2 = (const float*)d_in[13];
    float* out = (float*)d_out;

    int Nn = in_sizes[0] / 768;
    int E  = in_sizes[1] / 2;
    const int* esrc = ei;
    const int* edst = ei + E;
    int ET = E + Nn;

    // frontier caps (tiered to fit ws_size); expected actual: B~100, C~700,
    // E1~600, E2~85 — tier 1 is 5-10x margin.
    static const int tiers[4][4] = {
        {1024, 4096, 32768, 8192},
        { 512, 2048, 16384, 4096},
        { 256, 1536,  8192, 2048},
        { 128, 1024,  4096, 1024},
    };
    int capB = 128, capC = 1024, capE1 = 4096, capE2 = 1024;
    WsLayout L = makeLayout(Nn, capB, capC, capE1, capE2);
    for (int t = 0; t < 4; ++t) {
        WsLayout cand = makeLayout(Nn, tiers[t][0], tiers[t][1], tiers[t][2], tiers[t][3]);
        if (cand.total <= ws_size) {
            capB = tiers[t][0]; capC = tiers[t][1];
            capE1 = tiers[t][2]; capE2 = tiers[t][3];
            L = cand;
            break;
        }
    }

    char* ws = (char*)d_ws;
    int*   mapB     = (int*)  (ws + L.mapB);
    int*   mapC     = (int*)  (ws + L.mapC);
    int*   cnt      = (int*)  (ws + L.cntOff);
    float* den1     = (float*)(ws + L.den1);
    float* den2     = (float*)(ws + L.den2);
    float* out2acc  = (float*)(ws + L.out2acc);
    int*   listB    = (int*)  (ws + L.listB);
    int*   listC    = (int*)  (ws + L.listC);
    int*   e1srcRaw = (int*)  (ws + L.e1srcRaw);
    int*   e1dstB   = (int*)  (ws + L.e1dstB);
    int*   e1srcC   = (int*)  (ws + L.e1srcC);
    int*   e2srcRaw = (int*)  (ws + L.e2srcRaw);
    int*   e2dstA   = (int*)  (ws + L.e2dstA);
    int*   e2srcB   = (int*)  (ws + L.e2srcB);
    int*   e2dstB   = (int*)  (ws + L.e2dstB);
    float* e1exp    = (float*)(ws + L.e1exp);
    float* e2exp    = (float*)(ws + L.e2exp);
    float* XL1      = (float*)(ws + L.XL1);
    float* XR1      = (float*)(ws + L.XR1);
    float* H1       = (float*)(ws + L.H1);
    float* XL2      = (float*)(ws + L.XL2);
    float* XR2      = (float*)(ws + L.XR2);

    // init (every call: harness does not re-poison between replays)
    hipMemsetAsync(ws + L.mapB, 0xFF, (size_t)2 * Nn * 4, stream);
    hipMemsetAsync(ws + L.zeroBase, 0, L.zeroBytes, stream);

    int bgrid = (ET + 255) / 256;
    k_build2<<<bgrid, 256, 0, stream>>>(esrc, edst, E, Nn, mapB, listB, cnt,
                                        e2srcRaw, e2dstA, capB, capE2);
    k_build1<<<bgrid, 256, 0, stream>>>(esrc, edst, E, Nn, mapB, mapC, listC, cnt,
                                        e1srcRaw, e1dstB, capB, capC, capE1);
    int rmax = capE1 > capE2 ? capE1 : capE2;
    k_remap<<<(rmax + 255) / 256, 256, 0, stream>>>(mapB, mapC, cnt,
                                                    e1srcRaw, e1srcC,
                                                    e2srcRaw, e2srcB,
                                                    e2dstA, e2dstB,
                                                    capB, capC, capE1, capE2);
    k_zero<<<1024, 256, 0, stream>>>(XL1, XR1, H1, XL2, XR2, cnt, capB, capC);

    // layer-1 GEMMs (bias-free; biases folded downstream)
    k_gemm<<<dim3(3072 / 64, capC / 64, 2), 256, 0, stream>>>(
        x, 768, listC, Wl1, 3072, XL1, 3072, cnt, 1, capC, 768, 2);
    k_gemm<<<dim3(3072 / 64, capB / 64, 8), 256, 0, stream>>>(
        x, 768, listB, Wr1, 3072, XR1, 3072, cnt, 0, capB, 768, 8);

    k_att1<<<512, 256, 0, stream>>>(XL1, XR1, att1, bl1, br1, e1srcC, e1dstB,
                                    e1exp, den1, cnt, capE1);
    k_agg1<<<512, 256, 0, stream>>>(XL1, e1exp, den1, e1srcC, e1dstB, H1, cnt, capE1);
    k_hrelu<<<512, 256, 0, stream>>>(H1, bl1, bias1, cnt, capB);

    // layer-2 GEMMs
    k_gemm<<<dim3(768 / 64, capB / 64, 16), 256, 0, stream>>>(
        H1, 3072, nullptr, Wl2, 768, XL2, 768, cnt, 0, capB, 3072, 16);
    k_gemm<<<dim3(768 / 64, capB / 64, 16), 256, 0, stream>>>(
        H1, 3072, nullptr, Wr2, 768, XR2, 768, cnt, 0, capB, 3072, 16);

    k_att2<<<64, 256, 0, stream>>>(XL2, XR2, att2, bl2, br2, e2srcB, e2dstB, e2dstA,
                                   e2exp, den2, cnt, capE2);
    k_agg2<<<64, 256, 0, stream>>>(XL2, e2exp, den2, e2srcB, e2dstA, out2acc, cnt, capE2);
    k_out<<<(N_PATH * 768 + 255) / 256, 256, 0, stream>>>(out2acc, bl2, bias2, out);
}

// Round 2
// 153.406 us; speedup vs baseline: 1.6817x; 1.6817x over previous
//
#include <hip/hip_runtime.h>
#include <cstdint>
#include <cstddef>

#define N_PATH 14
#define NEG_SLOPE 0.2f

using u16 = unsigned short;
using u32 = unsigned int;
typedef __attribute__((ext_vector_type(4))) float f32x4;
typedef __attribute__((ext_vector_type(8))) short bf16x8;

__device__ __forceinline__ float lrelu(float v) { return v > 0.f ? v : NEG_SLOPE * v; }
__device__ __forceinline__ u16 f2bf(float f) {
    union { float f; u32 u; } c; c.f = f;
    return (u16)((c.u + 0x7FFFu + ((c.u >> 16) & 1u)) >> 16);
}
__device__ __forceinline__ float bf2f(u16 v) {
    union { u32 u; float f; } c; c.u = ((u32)v) << 16; return c.f;
}

// ------------------------------------------------------------------
// Frontier building. cnt[0]=nB, cnt[1]=nC, cnt[2]=nE1, cnt[3]=nE2
// ------------------------------------------------------------------
__global__ void k_build2(const int* __restrict__ esrc, const int* __restrict__ edst,
                         int E, int Nn,
                         int* __restrict__ mapB, int* __restrict__ listB,
                         int* __restrict__ cnt,
                         int* __restrict__ e2srcRaw, int* __restrict__ e2dstA,
                         int capB, int capE2)
{
    int e = blockIdx.x * blockDim.x + threadIdx.x;
    int ET = E + Nn;
    if (e >= ET) return;
    int s, d;
    if (e < E) { s = esrc[e]; d = edst[e]; } else { s = e - E; d = s; }
    if (d >= N_PATH) return;
    int slot = atomicAdd(&cnt[3], 1);
    if (slot < capE2) { e2srcRaw[slot] = s; e2dstA[slot] = d; }
    int old = atomicCAS(&mapB[s], -1, -2);
    if (old == -1) {
        int idx = atomicAdd(&cnt[0], 1);
        if (idx < capB) listB[idx] = s;
        mapB[s] = idx;
    }
}

__global__ void k_build1(const int* __restrict__ esrc, const int* __restrict__ edst,
                         int E, int Nn,
                         const int* __restrict__ mapB,
                         int* __restrict__ mapC, int* __restrict__ listC,
                         int* __restrict__ cnt,
                         int* __restrict__ e1srcRaw, int* __restrict__ e1dstB,
                         int capB, int capC, int capE1)
{
    int e = blockIdx.x * blockDim.x + threadIdx.x;
    int ET = E + Nn;
    if (e >= ET) return;
    int s, d;
    if (e < E) { s = esrc[e]; d = edst[e]; } else { s = e - E; d = s; }
    int b = mapB[d];
    if (b < 0 || b >= capB) return;
    int slot = atomicAdd(&cnt[2], 1);
    if (slot < capE1) { e1srcRaw[slot] = s; e1dstB[slot] = b; }
    int old = atomicCAS(&mapC[s], -1, -2);
    if (old == -1) {
        int idx = atomicAdd(&cnt[1], 1);
        if (idx < capC) listC[idx] = s;
        mapC[s] = idx;
    }
}

__global__ void k_remap(const int* __restrict__ mapB, const int* __restrict__ mapC,
                        const int* __restrict__ cnt, const int* __restrict__ listB,
                        const int* __restrict__ e1srcRaw, int* __restrict__ e1srcC,
                        const int* __restrict__ e2srcRaw, int* __restrict__ e2srcB,
                        const int* __restrict__ e2dstA, int* __restrict__ e2dstB,
                        int* __restrict__ listBinC,
                        int capB, int capC, int capE1, int capE2)
{
    int i = blockIdx.x * blockDim.x + threadIdx.x;
    int n1 = cnt[2]; if (n1 > capE1) n1 = capE1;
    int n2 = cnt[3]; if (n2 > capE2) n2 = capE2;
    int nB = cnt[0]; if (nB > capB) nB = capB;
    if (i < n1) {
        int c = mapC[e1srcRaw[i]];
        if (c < 0) c = 0; if (c >= capC) c = capC - 1;
        e1srcC[i] = c;
    }
    if (i < n2) {
        int b = mapB[e2srcRaw[i]];
        if (b < 0) b = 0; if (b >= capB) b = capB - 1;
        e2srcB[i] = b;
        int bd = mapB[e2dstA[i]];
        if (bd < 0) bd = 0; if (bd >= capB) bd = capB - 1;
        e2dstB[i] = bd;
    }
    if (i < nB) {
        int c = mapC[listB[i]];
        if (c < 0) c = 0; if (c >= capC) c = capC - 1;
        listBinC[i] = c;
    }
}

// ------------------------------------------------------------------
// Weight transpose+convert: W[k][n] f32 -> Wt[n][k] bf16 (all 4 matrices)
// ------------------------------------------------------------------
__global__ __launch_bounds__(256)
void k_convW(const float* __restrict__ Wl1, const float* __restrict__ Wr1,
             const float* __restrict__ Wl2, const float* __restrict__ Wr2,
             u16* __restrict__ Wl1t, u16* __restrict__ Wr1t, u16* __restrict__ W2t)
{
    __shared__ float tile[64][65];
    int mz = blockIdx.y;
    const float* src; u16* dst; int IR, IC;
    if      (mz == 0) { src = Wl1; dst = Wl1t;                      IR = 768;  IC = 3072; }
    else if (mz == 1) { src = Wr1; dst = Wr1t;                      IR = 768;  IC = 3072; }
    else if (mz == 2) { src = Wl2; dst = W2t;                       IR = 3072; IC = 768;  }
    else              { src = Wr2; dst = W2t + (size_t)768 * 3072;  IR = 3072; IC = 768;  }
    int tilesC = IC >> 6;
    int tr = blockIdx.x / tilesC, tc = blockIdx.x % tilesC;
    int t = threadIdx.x;
    int rr = t >> 4, cc = (t & 15) << 2;
    #pragma unroll
    for (int p = 0; p < 4; ++p) {
        int r = p * 16 + rr;
        float4 v = *reinterpret_cast<const float4*>(src + (size_t)(tr * 64 + r) * IC + tc * 64 + cc);
        tile[r][cc + 0] = v.x; tile[r][cc + 1] = v.y;
        tile[r][cc + 2] = v.z; tile[r][cc + 3] = v.w;
    }
    __syncthreads();
    #pragma unroll
    for (int p = 0; p < 4; ++p) {
        int r = p * 16 + rr;  // out row within tile (= source col)
        u32 lo = (u32)f2bf(tile[cc + 0][r]) | ((u32)f2bf(tile[cc + 1][r]) << 16);
        u32 hi = (u32)f2bf(tile[cc + 2][r]) | ((u32)f2bf(tile[cc + 3][r]) << 16);
        uint2 o; o.x = lo; o.y = hi;
        *reinterpret_cast<uint2*>(dst + (size_t)(tc * 64 + r) * IR + tr * 64 + cc) = o;
    }
}

// gather x rows (listC) -> dense bf16 Abf [capC][768]
__global__ void k_gather_x(const float* __restrict__ x, const int* __restrict__ listC,
                           const int* __restrict__ cnt, int capC, u16* __restrict__ Abf)
{
    int row = blockIdx.x;
    int nC = cnt[1]; if (nC > capC) nC = capC;
    if (row >= nC) return;
    int g = listC[row];
    int t = threadIdx.x;
    if (t * 4 < 768) {
        float4 v = *reinterpret_cast<const float4*>(x + (size_t)g * 768 + t * 4);
        u32 lo = (u32)f2bf(v.x) | ((u32)f2bf(v.y) << 16);
        u32 hi = (u32)f2bf(v.z) | ((u32)f2bf(v.w) << 16);
        uint2 o; o.x = lo; o.y = hi;
        *reinterpret_cast<uint2*>(Abf + (size_t)row * 768 + t * 4) = o;
    }
}

// ------------------------------------------------------------------
// bf16 MFMA GEMM: C[r, n] (+)= sum_k A[g(r), k] * Wt[n, k]
// 64x64 tile, 4 waves (2x2), BK=64, 16x16x32 bf16 MFMA, T2 XOR swizzle.
// mode: 0 = f32 store, 1 = f32 atomicAdd, 2 = bf16 store
// ------------------------------------------------------------------
__global__ __launch_bounds__(256)
void k_gemm_bf16(const u16* __restrict__ A, int lda, const int* __restrict__ gather,
                 const u16* __restrict__ Wt, int ldb,
                 void* __restrict__ Cout, int ldc, int mode,
                 const int* __restrict__ cnt, int cntIdx, int capM, int kchunk)
{
    __shared__ __align__(16) u16 As[64 * 64];
    __shared__ __align__(16) u16 Bs[64 * 64];
    int M = cnt[cntIdx]; if (M > capM) M = capM;
    int m0 = blockIdx.y * 64;
    if (m0 >= M) return;
    int n0 = blockIdx.x * 64;
    int k0 = blockIdx.z * kchunk;
    int t = threadIdx.x;
    int lane = t & 63, wave = t >> 6;
    int wr = wave >> 1, wc = wave & 1;
    int lrow = lane & 15, lhi = lane >> 4;

    int chunk = t & 7;
    int rowp[2], aRow[2], wIdx[2];
    #pragma unroll
    for (int p = 0; p < 2; ++p) {
        rowp[p] = p * 32 + (t >> 3);
        int ar = m0 + rowp[p]; if (ar >= M) ar = M - 1;
        aRow[p] = gather ? gather[ar] : ar;
        wIdx[p] = rowp[p] * 64 + ((chunk ^ (rowp[p] & 7)) << 3);
    }

    int aIdx[2][2], bIdx[2][2];
    #pragma unroll
    for (int mi = 0; mi < 2; ++mi)
        #pragma unroll
        for (int ks = 0; ks < 2; ++ks) {
            int ra = wr * 32 + mi * 16 + lrow;
            aIdx[mi][ks] = ra * 64 + ((((ks << 2) | lhi) ^ (ra & 7)) << 3);
            int rb = wc * 32 + mi * 16 + lrow;
            bIdx[mi][ks] = rb * 64 + ((((ks << 2) | lhi) ^ (rb & 7)) << 3);
        }

    f32x4 acc[2][2];
    #pragma unroll
    for (int i = 0; i < 2; ++i)
        #pragma unroll
        for (int j = 0; j < 2; ++j)
            acc[i][j] = (f32x4){0.f, 0.f, 0.f, 0.f};

    for (int kt = 0; kt < kchunk; kt += 64) {
        int kb = k0 + kt + chunk * 8;
        #pragma unroll
        for (int p = 0; p < 2; ++p) {
            uint4 av = *reinterpret_cast<const uint4*>(A + (size_t)aRow[p] * lda + kb);
            *reinterpret_cast<uint4*>(&As[wIdx[p]]) = av;
            uint4 bv = *reinterpret_cast<const uint4*>(Wt + (size_t)(n0 + rowp[p]) * ldb + kb);
            *reinterpret_cast<uint4*>(&Bs[wIdx[p]]) = bv;
        }
        __syncthreads();
        #pragma unroll
        for (int ks = 0; ks < 2; ++ks) {
            bf16x8 a0 = *reinterpret_cast<const bf16x8*>(&As[aIdx[0][ks]]);
            bf16x8 a1 = *reinterpret_cast<const bf16x8*>(&As[aIdx[1][ks]]);
            bf16x8 b0 = *reinterpret_cast<const bf16x8*>(&Bs[bIdx[0][ks]]);
            bf16x8 b1 = *reinterpret_cast<const bf16x8*>(&Bs[bIdx[1][ks]]);
            acc[0][0] = __builtin_amdgcn_mfma_f32_16x16x32_bf16(a0, b0, acc[0][0], 0, 0, 0);
            acc[0][1] = __builtin_amdgcn_mfma_f32_16x16x32_bf16(a0, b1, acc[0][1], 0, 0, 0);
            acc[1][0] = __builtin_amdgcn_mfma_f32_16x16x32_bf16(a1, b0, acc[1][0], 0, 0, 0);
            acc[1][1] = __builtin_amdgcn_mfma_f32_16x16x32_bf16(a1, b1, acc[1][1], 0, 0, 0);
        }
        __syncthreads();
    }

    #pragma unroll
    for (int mi = 0; mi < 2; ++mi)
        #pragma unroll
        for (int ni = 0; ni < 2; ++ni) {
            int gc = n0 + wc * 32 + ni * 16 + lrow;
            #pragma unroll
            for (int j = 0; j < 4; ++j) {
                int gr = m0 + wr * 32 + mi * 16 + lhi * 4 + j;
                if (gr < M) {
                    float v = acc[mi][ni][j];
                    if (mode == 2)      ((u16*)Cout)[(size_t)gr * ldc + gc] = f2bf(v);
                    else if (mode == 1) atomicAdd(&((float*)Cout)[(size_t)gr * ldc + gc], v);
                    else                ((float*)Cout)[(size_t)gr * ldc + gc] = v;
                }
            }
        }
}

// ------------------------------------------------------------------
// Layer-1 edge kernels (bf16 features). One wave per edge.
// ------------------------------------------------------------------
__global__ void k_att1(const u16* __restrict__ XL1, const u16* __restrict__ XR1,
                       const float* __restrict__ att1,
                       const float* __restrict__ bl1, const float* __restrict__ br1,
                       const int* __restrict__ e1srcC, const int* __restrict__ e1dstB,
                       float* __restrict__ e1exp, float* __restrict__ den1,
                       const int* __restrict__ cnt, int capE1)
{
    int nE = cnt[2]; if (nE > capE1) nE = capE1;
    int lane = threadIdx.x & 63;
    int wid = (blockIdx.x * blockDim.x + threadIdx.x) >> 6;
    int nW  = (gridDim.x * blockDim.x) >> 6;
    for (int i = wid; i < nE; i += nW) {
        int c = e1srcC[i], b = e1dstB[i];
        const u16* xl = XL1 + (size_t)c * 3072;
        const u16* xr = XR1 + (size_t)b * 3072;
        float part[4] = {0.f, 0.f, 0.f, 0.f};
        #pragma unroll
        for (int h = 0; h < 4; ++h) {
            int base = h * 768;
            #pragma unroll
            for (int j = 0; j < 12; ++j) {
                int k = base + j * 64 + lane;
                float s = bf2f(xl[k]) + bf2f(xr[k]) + bl1[k] + br1[k];
                s = lrelu(s);
                part[h] = fmaf(att1[k], s, part[h]);
            }
        }
        #pragma unroll
        for (int h = 0; h < 4; ++h) {
            float v = part[h];
            for (int off = 32; off > 0; off >>= 1) v += __shfl_xor(v, off);
            if (lane == 0) {
                float ex = expf(v);
                e1exp[i * 4 + h] = ex;
                atomicAdd(&den1[b * 4 + h], ex);
            }
        }
    }
}

__global__ void k_agg1(const u16* __restrict__ XL1,
                       const float* __restrict__ e1exp, const float* __restrict__ den1,
                       const int* __restrict__ e1srcC, const int* __restrict__ e1dstB,
                       float* __restrict__ H1acc,
                       const int* __restrict__ cnt, int capE1)
{
    int nE = cnt[2]; if (nE > capE1) nE = capE1;
    int lane = threadIdx.x & 63;
    int wid = (blockIdx.x * blockDim.x + threadIdx.x) >> 6;
    int nW  = (gridDim.x * blockDim.x) >> 6;
    for (int i = wid; i < nE; i += nW) {
        int c = e1srcC[i], b = e1dstB[i];
        const u16* xl = XL1 + (size_t)c * 3072;
        float* hb = H1acc + (size_t)b * 3072;
        float al[4];
        #pragma unroll
        for (int h = 0; h < 4; ++h)
            al[h] = e1exp[i * 4 + h] / (den1[b * 4 + h] + 1e-16f);
        #pragma unroll
        for (int h = 0; h < 4; ++h) {
            int base = h * 768;
            #pragma unroll
            for (int j = 0; j < 12; ++j) {
                int k = base + j * 64 + lane;
                atomicAdd(&hb[k], al[h] * bf2f(xl[k]));
            }
        }
    }
}

// H1bf = bf16(relu(H1acc + bl1 + bias1))
__global__ void k_hrelu(const float* __restrict__ H1acc,
                        const float* __restrict__ bl1, const float* __restrict__ bias1,
                        u16* __restrict__ H1bf,
                        const int* __restrict__ cnt, int capB)
{
    int nB = cnt[0]; if (nB > capB) nB = capB;
    size_t total = (size_t)nB * 3072;
    size_t stride = (size_t)gridDim.x * blockDim.x;
    for (size_t i = (size_t)blockIdx.x * blockDim.x + threadIdx.x; i < total; i += stride) {
        int col = (int)(i % 3072);
        float v = H1acc[i] + bl1[col] + bias1[col];
        H1bf[i] = f2bf(v > 0.f ? v : 0.f);
    }
}

// ------------------------------------------------------------------
// Layer-2 edge kernels (XLR2 f32: [b][0..767]=XL2, [b][768..1535]=XR2)
// ------------------------------------------------------------------
__global__ void k_att2(const float* __restrict__ XLR2,
                       const float* __restrict__ att2,
                       const float* __restrict__ bl2, const float* __restrict__ br2,
                       const int* __restrict__ e2srcB, const int* __restrict__ e2dstB,
                       const int* __restrict__ e2dstA,
                       float* __restrict__ e2exp, float* __restrict__ den2,
                       const int* __restrict__ cnt, int capE2)
{
    int nE = cnt[3]; if (nE > capE2) nE = capE2;
    int lane = threadIdx.x & 63;
    int wid = (blockIdx.x * blockDim.x + threadIdx.x) >> 6;
    int nW  = (gridDim.x * blockDim.x) >> 6;
    for (int i = wid; i < nE; i += nW) {
        int bs = e2srcB[i], bd = e2dstB[i], a = e2dstA[i];
        const float* xl = XLR2 + (size_t)bs * 1536;
        const float* xr = XLR2 + (size_t)bd * 1536 + 768;
        float part = 0.f;
        #pragma unroll
        for (int j = 0; j < 12; ++j) {
            int k = j * 64 + lane;
            float s = xl[k] + xr[k] + bl2[k] + br2[k];
            s = lrelu(s);
            part = fmaf(att2[k], s, part);
        }
        for (int off = 32; off > 0; off >>= 1) part += __shfl_xor(part, off);
        if (lane == 0) {
            float ex = expf(part);
            e2exp[i] = ex;
            atomicAdd(&den2[a], ex);
        }
    }
}

__global__ void k_agg2(const float* __restrict__ XLR2,
                       const float* __restrict__ e2exp, const float* __restrict__ den2,
                       const int* __restrict__ e2srcB, const int* __restrict__ e2dstA,
                       float* __restrict__ out2acc,
                       const int* __restrict__ cnt, int capE2)
{
    int nE = cnt[3]; if (nE > capE2) nE = capE2;
    int lane = threadIdx.x & 63;
    int wid = (blockIdx.x * blockDim.x + threadIdx.x) >> 6;
    int nW  = (gridDim.x * blockDim.x) >> 6;
    for (int i = wid; i < nE; i += nW) {
        int bs = e2srcB[i], a = e2dstA[i];
        const float* xl = XLR2 + (size_t)bs * 1536;
        float al = e2exp[i] / (den2[a] + 1e-16f);
        #pragma unroll
        for (int j = 0; j < 12; ++j) {
            int k = j * 64 + lane;
            atomicAdd(&out2acc[a * 768 + k], al * xl[k]);
        }
    }
}

__global__ void k_out(const float* __restrict__ out2acc,
                      const float* __restrict__ bl2, const float* __restrict__ bias2,
                      float* __restrict__ out)
{
    int i = blockIdx.x * blockDim.x + threadIdx.x;
    if (i < N_PATH * 768) {
        int col = i % 768;
        out[i] = out2acc[i] + bl2[col] + bias2[col];
    }
}

// ------------------------------------------------------------------
// Host side
// ------------------------------------------------------------------
struct Lay {
    size_t mapB, mapC;
    size_t zbase, zbytes;
    size_t cnt, den1, den2, out2acc, XLR2, H1acc;
    size_t listB, listC, listBinC;
    size_t e1sR, e1dB, e1sC, e2sR, e2dA, e2sB, e2dB;
    size_t e1exp, e2exp;
    size_t Abf, H1bf, Wl1t, Wr1t, W2t, XL1, XR1;
    size_t total;
};

static Lay makeLayout(int Nn, int cB, int cC, int cE1, int cE2)
{
    Lay L{};
    size_t off = 0;
    auto take = [&](size_t bytes) { size_t o = (off + 255) & ~(size_t)255; off = o + bytes; return o; };
    L.mapB = take((size_t)2 * Nn * 4);
    L.mapC = L.mapB + (size_t)Nn * 4;
    // contiguous zero region
    size_t zb = 64 + (size_t)cB * 4 * 4 + 64 + (size_t)N_PATH * 768 * 4
              + (size_t)cB * 1536 * 4 + (size_t)cB * 3072 * 4;
    L.zbase = take(zb); L.zbytes = zb;
    L.cnt     = L.zbase;
    L.den1    = L.cnt + 64;
    L.den2    = L.den1 + (size_t)cB * 4 * 4;
    L.out2acc = L.den2 + 64;
    L.XLR2    = L.out2acc + (size_t)N_PATH * 768 * 4;
    L.H1acc   = L.XLR2 + (size_t)cB * 1536 * 4;
    L.listB    = take((size_t)cB * 4);
    L.listC    = take((size_t)cC * 4);
    L.listBinC = take((size_t)cB * 4);
    L.e1sR = take((size_t)cE1 * 4);
    L.e1dB = take((size_t)cE1 * 4);
    L.e1sC = take((size_t)cE1 * 4);
    L.e2sR = take((size_t)cE2 * 4);
    L.e2dA = take((size_t)cE2 * 4);
    L.e2sB = take((size_t)cE2 * 4);
    L.e2dB = take((size_t)cE2 * 4);
    L.e1exp = take((size_t)cE1 * 4 * 4);
    L.e2exp = take((size_t)cE2 * 4);
    L.Abf  = take((size_t)cC * 768 * 2);
    L.H1bf = take((size_t)cB * 3072 * 2);
    L.Wl1t = take((size_t)3072 * 768 * 2);
    L.Wr1t = take((size_t)3072 * 768 * 2);
    L.W2t  = take((size_t)1536 * 3072 * 2);
    L.XL1  = take((size_t)cC * 3072 * 2);
    L.XR1  = take((size_t)cB * 3072 * 2);
    L.total = off;
    return L;
}

extern "C" void kernel_launch(void* const* d_in, const int* in_sizes, int n_in,
                              void* d_out, int out_size, void* d_ws, size_t ws_size,
                              hipStream_t stream)
{
    const float* x     = (const float*)d_in[0];
    const int*   ei    = (const int*)  d_in[1];
    const float* Wl1   = (const float*)d_in[2];
    const float* bl1   = (const float*)d_in[3];
    const float* Wr1   = (const float*)d_in[4];
    const float* br1   = (const float*)d_in[5];
    const float* att1  = (const float*)d_in[6];
    const float* bias1 = (const float*)d_in[7];
    const float* Wl2   = (const float*)d_in[8];
    const float* bl2   = (const float*)d_in[9];
    const float* Wr2   = (const float*)d_in[10];
    const float* br2   = (const float*)d_in[11];
    const float* att2  = (const float*)d_in[12];
    const float* bias2 = (const float*)d_in[13];
    float* out = (float*)d_out;

    int Nn = in_sizes[0] / 768;
    int E  = in_sizes[1] / 2;
    const int* esrc = ei;
    const int* edst = ei + E;
    int ET = E + Nn;

    // expected actual sizes: B~100, C~620, E1~600, E2~85
    static const int tiers[2][4] = {
        {256, 1024, 4096, 1024},
        {128,  768, 2048,  512},
    };
    int capB = tiers[1][0], capC = tiers[1][1], capE1 = tiers[1][2], capE2 = tiers[1][3];
    Lay L = makeLayout(Nn, capB, capC, capE1, capE2);
    for (int t = 0; t < 2; ++t) {
        Lay cand = makeLayout(Nn, tiers[t][0], tiers[t][1], tiers[t][2], tiers[t][3]);
        if (cand.total <= ws_size) {
            capB = tiers[t][0]; capC = tiers[t][1];
            capE1 = tiers[t][2]; capE2 = tiers[t][3];
            L = cand;
            break;
        }
    }

    char* ws = (char*)d_ws;
    int*   mapB     = (int*)  (ws + L.mapB);
    int*   mapC     = (int*)  (ws + L.mapC);
    int*   cnt      = (int*)  (ws + L.cnt);
    float* den1     = (float*)(ws + L.den1);
    float* den2     = (float*)(ws + L.den2);
    float* out2acc  = (float*)(ws + L.out2acc);
    float* XLR2     = (float*)(ws + L.XLR2);
    float* H1acc    = (float*)(ws + L.H1acc);
    int*   listB    = (int*)  (ws + L.listB);
    int*   listC    = (int*)  (ws + L.listC);
    int*   listBinC = (int*)  (ws + L.listBinC);
    int*   e1srcRaw = (int*)  (ws + L.e1sR);
    int*   e1dstB   = (int*)  (ws + L.e1dB);
    int*   e1srcC   = (int*)  (ws + L.e1sC);
    int*   e2srcRaw = (int*)  (ws + L.e2sR);
    int*   e2dstA   = (int*)  (ws + L.e2dA);
    int*   e2srcB   = (int*)  (ws + L.e2sB);
    int*   e2dstB   = (int*)  (ws + L.e2dB);
    float* e1exp    = (float*)(ws + L.e1exp);
    float* e2exp    = (float*)(ws + L.e2exp);
    u16*   Abf      = (u16*)  (ws + L.Abf);
    u16*   H1bf     = (u16*)  (ws + L.H1bf);
    u16*   Wl1t     = (u16*)  (ws + L.Wl1t);
    u16*   Wr1t     = (u16*)  (ws + L.Wr1t);
    u16*   W2t      = (u16*)  (ws + L.W2t);
    u16*   XL1      = (u16*)  (ws + L.XL1);
    u16*   XR1      = (u16*)  (ws + L.XR1);

    hipMemsetAsync(ws + L.mapB, 0xFF, (size_t)2 * Nn * 4, stream);
    hipMemsetAsync(ws + L.zbase, 0, L.zbytes, stream);

    int bgrid = (ET + 255) / 256;
    k_build2<<<bgrid, 256, 0, stream>>>(esrc, edst, E, Nn, mapB, listB, cnt,
                                        e2srcRaw, e2dstA, capB, capE2);
    k_build1<<<bgrid, 256, 0, stream>>>(esrc, edst, E, Nn, mapB, mapC, listC, cnt,
                                        e1srcRaw, e1dstB, capB, capC, capE1);
    k_remap<<<(capE1 + 255) / 256, 256, 0, stream>>>(mapB, mapC, cnt, listB,
                                                     e1srcRaw, e1srcC,
                                                     e2srcRaw, e2srcB,
                                                     e2dstA, e2dstB, listBinC,
                                                     capB, capC, capE1, capE2);

    k_convW<<<dim3(576, 4), 256, 0, stream>>>(Wl1, Wr1, Wl2, Wr2, Wl1t, Wr1t, W2t);
    k_gather_x<<<capC, 192, 0, stream>>>(x, listC, cnt, capC, Abf);

    // XL1 = Abf @ Wl1 (bf16 out), XR1 = Abf[listBinC] @ Wr1 (bf16 out)
    k_gemm_bf16<<<dim3(48, capC / 64, 1), 256, 0, stream>>>(
        Abf, 768, nullptr, Wl1t, 768, XL1, 3072, 2, cnt, 1, capC, 768);
    k_gemm_bf16<<<dim3(48, capB / 64, 1), 256, 0, stream>>>(
        Abf, 768, listBinC, Wr1t, 768, XR1, 3072, 2, cnt, 0, capB, 768);

    k_att1<<<128, 256, 0, stream>>>(XL1, XR1, att1, bl1, br1, e1srcC, e1dstB,
                                    e1exp, den1, cnt, capE1);
    k_agg1<<<128, 256, 0, stream>>>(XL1, e1exp, den1, e1srcC, e1dstB, H1acc, cnt, capE1);
    k_hrelu<<<256, 256, 0, stream>>>(H1acc, bl1, bias1, H1bf, cnt, capB);

    // [XL2|XR2] = H1bf @ [Wl2|Wr2]  (f32 atomic, K-split 4)
    k_gemm_bf16<<<dim3(24, capB / 64, 4), 256, 0, stream>>>(
        H1bf, 3072, nullptr, W2t, 3072, XLR2, 1536, 1, cnt, 0, capB, 768);

    k_att2<<<16, 256, 0, stream>>>(XLR2, att2, bl2, br2, e2srcB, e2dstB, e2dstA,
                                   e2exp, den2, cnt, capE2);
    k_agg2<<<16, 256, 0, stream>>>(XLR2, e2exp, den2, e2srcB, e2dstA, out2acc, cnt, capE2);
    k_out<<<(N_PATH * 768 + 255) / 256, 256, 0, stream>>>(out2acc, bl2, bias2, out);
}

// Round 3
// 110.983 us; speedup vs baseline: 2.3245x; 1.3822x over previous
//
#include <hip/hip_runtime.h>
#include <cstdint>
#include <cstddef>

#define N_PATH 14
#define NEG_SLOPE 0.2f
#define BINW 128

using u16 = unsigned short;
using u32 = unsigned int;
typedef __attribute__((ext_vector_type(4))) float f32x4;
typedef __attribute__((ext_vector_type(8))) short bf16x8;

__device__ __forceinline__ float lrelu(float v) { return v > 0.f ? v : NEG_SLOPE * v; }
__device__ __forceinline__ u16 f2bf(float f) {
    union { float f; u32 u; } c; c.f = f;
    return (u16)((c.u + 0x7FFFu + ((c.u >> 16) & 1u)) >> 16);
}
__device__ __forceinline__ float bf2f(u16 v) {
    union { u32 u; float f; } c; c.u = ((u32)v) << 16; return c.f;
}

// ------------------------------------------------------------------
// Frontier building. cnt[0]=nB, cnt[1]=nC
// ------------------------------------------------------------------
__global__ void k_build2(const int* __restrict__ esrc, const int* __restrict__ edst,
                         int E, int Nn,
                         int* __restrict__ mapB, int* __restrict__ listB,
                         int* __restrict__ cnt,
                         int* __restrict__ deg2, int* __restrict__ e2bin,
                         int capB)
{
    int e = blockIdx.x * blockDim.x + threadIdx.x;
    int ET = E + Nn;
    if (e >= ET) return;
    int s, d;
    if (e < E) { s = esrc[e]; d = edst[e]; } else { s = e - E; d = s; }
    if (d >= N_PATH) return;
    int slot = atomicAdd(&deg2[d], 1);
    if (slot < BINW) e2bin[d * BINW + slot] = s;
    int old = atomicCAS(&mapB[s], -1, -2);
    if (old == -1) {
        int idx = atomicAdd(&cnt[0], 1);
        if (idx < capB) listB[idx] = s;
        mapB[s] = idx;
    }
}

__global__ void k_build1(const int* __restrict__ esrc, const int* __restrict__ edst,
                         int E, int Nn,
                         const int* __restrict__ mapB,
                         int* __restrict__ mapC, int* __restrict__ listC,
                         int* __restrict__ cnt,
                         int* __restrict__ deg1, int* __restrict__ e1bin,
                         int capB, int capC)
{
    int e = blockIdx.x * blockDim.x + threadIdx.x;
    int ET = E + Nn;
    if (e >= ET) return;
    int s, d;
    if (e < E) { s = esrc[e]; d = edst[e]; } else { s = e - E; d = s; }
    int b = mapB[d];
    if (b < 0 || b >= capB) return;
    int slot = atomicAdd(&deg1[b], 1);
    if (slot < BINW) e1bin[b * BINW + slot] = s;
    int old = atomicCAS(&mapC[s], -1, -2);
    if (old == -1) {
        int idx = atomicAdd(&cnt[1], 1);
        if (idx < capC) listC[idx] = s;
        mapC[s] = idx;
    }
}

// ------------------------------------------------------------------
// Weight transpose+convert: W[k][n] f32 -> Wt[n][k] bf16
// ------------------------------------------------------------------
__global__ __launch_bounds__(256)
void k_convW(const float* __restrict__ Wl1, const float* __restrict__ Wr1,
             const float* __restrict__ Wl2, const float* __restrict__ Wr2,
             u16* __restrict__ Wl1t, u16* __restrict__ Wr1t, u16* __restrict__ W2t)
{
    __shared__ float tile[64][65];
    int mz = blockIdx.y;
    const float* src; u16* dst; int IR, IC;
    if      (mz == 0) { src = Wl1; dst = Wl1t;                      IR = 768;  IC = 3072; }
    else if (mz == 1) { src = Wr1; dst = Wr1t;                      IR = 768;  IC = 3072; }
    else if (mz == 2) { src = Wl2; dst = W2t;                       IR = 3072; IC = 768;  }
    else              { src = Wr2; dst = W2t + (size_t)768 * 3072;  IR = 3072; IC = 768;  }
    int tilesC = IC >> 6;
    int tr = blockIdx.x / tilesC, tc = blockIdx.x % tilesC;
    int t = threadIdx.x;
    int rr = t >> 4, cc = (t & 15) << 2;
    #pragma unroll
    for (int p = 0; p < 4; ++p) {
        int r = p * 16 + rr;
        float4 v = *reinterpret_cast<const float4*>(src + (size_t)(tr * 64 + r) * IC + tc * 64 + cc);
        tile[r][cc + 0] = v.x; tile[r][cc + 1] = v.y;
        tile[r][cc + 2] = v.z; tile[r][cc + 3] = v.w;
    }
    __syncthreads();
    #pragma unroll
    for (int p = 0; p < 4; ++p) {
        int r = p * 16 + rr;
        u32 lo = (u32)f2bf(tile[cc + 0][r]) | ((u32)f2bf(tile[cc + 1][r]) << 16);
        u32 hi = (u32)f2bf(tile[cc + 2][r]) | ((u32)f2bf(tile[cc + 3][r]) << 16);
        uint2 o; o.x = lo; o.y = hi;
        *reinterpret_cast<uint2*>(dst + (size_t)(tc * 64 + r) * IR + tr * 64 + cc) = o;
    }
}

// ------------------------------------------------------------------
// bf16 MFMA GEMM: C[r, n] (+)= sum_k A[g(r), k] * Wt[n, k]  (+ bias)
// 64x64 tile, 4 waves (2x2), BK=64, 16x16x32 bf16 MFMA, XOR swizzle.
// aF32: A is f32 (converted during staging). mode: 1 = f32 atomicAdd
// (bias added only when blockIdx.z==0), 2 = bf16 store.
// bias column c: c < nsplit ? biasA[c] : biasB[c-nsplit]
// ------------------------------------------------------------------
__global__ __launch_bounds__(256)
void k_gemm_bf16(const void* __restrict__ A, int lda, int aF32,
                 const int* __restrict__ gather,
                 const u16* __restrict__ Wt, int ldb,
                 void* __restrict__ Cout, int ldc, int mode,
                 const float* __restrict__ biasA, const float* __restrict__ biasB,
                 int nsplit,
                 const int* __restrict__ cnt, int cntIdx, int capM, int kchunk)
{
    __shared__ __align__(16) u16 As[64 * 64];
    __shared__ __align__(16) u16 Bs[64 * 64];
    int M = cnt[cntIdx]; if (M > capM) M = capM;
    int m0 = blockIdx.y * 64;
    if (m0 >= M) return;
    int n0 = blockIdx.x * 64;
    int k0 = blockIdx.z * kchunk;
    int t = threadIdx.x;
    int lane = t & 63, wave = t >> 6;
    int wr = wave >> 1, wc = wave & 1;
    int lrow = lane & 15, lhi = lane >> 4;

    int chunk = t & 7;
    int rowp[2], aRow[2], wIdx[2];
    #pragma unroll
    for (int p = 0; p < 2; ++p) {
        rowp[p] = p * 32 + (t >> 3);
        int ar = m0 + rowp[p]; if (ar >= M) ar = M - 1;
        aRow[p] = gather ? gather[ar] : ar;
        wIdx[p] = rowp[p] * 64 + ((chunk ^ (rowp[p] & 7)) << 3);
    }

    int aIdx[2][2], bIdx[2][2];
    #pragma unroll
    for (int mi = 0; mi < 2; ++mi)
        #pragma unroll
        for (int ks = 0; ks < 2; ++ks) {
            int ra = wr * 32 + mi * 16 + lrow;
            aIdx[mi][ks] = ra * 64 + ((((ks << 2) | lhi) ^ (ra & 7)) << 3);
            int rb = wc * 32 + mi * 16 + lrow;
            bIdx[mi][ks] = rb * 64 + ((((ks << 2) | lhi) ^ (rb & 7)) << 3);
        }

    f32x4 acc[2][2];
    #pragma unroll
    for (int i = 0; i < 2; ++i)
        #pragma unroll
        for (int j = 0; j < 2; ++j)
            acc[i][j] = (f32x4){0.f, 0.f, 0.f, 0.f};

    for (int kt = 0; kt < kchunk; kt += 64) {
        int kb = k0 + kt + chunk * 8;
        #pragma unroll
        for (int p = 0; p < 2; ++p) {
            uint4 av;
            if (aF32) {
                const float* ap = (const float*)A + (size_t)aRow[p] * lda + kb;
                float4 f0 = *reinterpret_cast<const float4*>(ap);
                float4 f1 = *reinterpret_cast<const float4*>(ap + 4);
                av.x = (u32)f2bf(f0.x) | ((u32)f2bf(f0.y) << 16);
                av.y = (u32)f2bf(f0.z) | ((u32)f2bf(f0.w) << 16);
                av.z = (u32)f2bf(f1.x) | ((u32)f2bf(f1.y) << 16);
                av.w = (u32)f2bf(f1.z) | ((u32)f2bf(f1.w) << 16);
            } else {
                av = *reinterpret_cast<const uint4*>((const u16*)A + (size_t)aRow[p] * lda + kb);
            }
            *reinterpret_cast<uint4*>(&As[wIdx[p]]) = av;
            uint4 bv = *reinterpret_cast<const uint4*>(Wt + (size_t)(n0 + rowp[p]) * ldb + kb);
            *reinterpret_cast<uint4*>(&Bs[wIdx[p]]) = bv;
        }
        __syncthreads();
        #pragma unroll
        for (int ks = 0; ks < 2; ++ks) {
            bf16x8 a0 = *reinterpret_cast<const bf16x8*>(&As[aIdx[0][ks]]);
            bf16x8 a1 = *reinterpret_cast<const bf16x8*>(&As[aIdx[1][ks]]);
            bf16x8 b0 = *reinterpret_cast<const bf16x8*>(&Bs[bIdx[0][ks]]);
            bf16x8 b1 = *reinterpret_cast<const bf16x8*>(&Bs[bIdx[1][ks]]);
            acc[0][0] = __builtin_amdgcn_mfma_f32_16x16x32_bf16(a0, b0, acc[0][0], 0, 0, 0);
            acc[0][1] = __builtin_amdgcn_mfma_f32_16x16x32_bf16(a0, b1, acc[0][1], 0, 0, 0);
            acc[1][0] = __builtin_amdgcn_mfma_f32_16x16x32_bf16(a1, b0, acc[1][0], 0, 0, 0);
            acc[1][1] = __builtin_amdgcn_mfma_f32_16x16x32_bf16(a1, b1, acc[1][1], 0, 0, 0);
        }
        __syncthreads();
    }

    bool addBias = (mode == 2) || (blockIdx.z == 0);
    #pragma unroll
    for (int mi = 0; mi < 2; ++mi)
        #pragma unroll
        for (int ni = 0; ni < 2; ++ni) {
            int gc = n0 + wc * 32 + ni * 16 + lrow;
            float bv = addBias ? (gc < nsplit ? biasA[gc] : biasB[gc - nsplit]) : 0.f;
            #pragma unroll
            for (int j = 0; j < 4; ++j) {
                int gr = m0 + wr * 32 + mi * 16 + lhi * 4 + j;
                if (gr < M) {
                    float v = acc[mi][ni][j] + bv;
                    if (mode == 2) ((u16*)Cout)[(size_t)gr * ldc + gc] = f2bf(v);
                    else           atomicAdd(&((float*)Cout)[(size_t)gr * ldc + gc], v);
                }
            }
        }
}

// ------------------------------------------------------------------
// Fused layer-1 edge phase: one block per B node, 4 waves = 4 heads.
// Lane owns 12 contiguous channels (t*12 .. t*12+11).
// attention + softmax + aggregate + bias1 + relu + bf16 store, no atomics.
// ------------------------------------------------------------------
__global__ __launch_bounds__(256)
void k_fused1(const u16* __restrict__ XL1, const u16* __restrict__ XR1,
              const float* __restrict__ att1, const float* __restrict__ bias1,
              const int* __restrict__ mapC,
              const int* __restrict__ deg1, const int* __restrict__ e1bin,
              u16* __restrict__ H1bf,
              const int* __restrict__ cnt, int capB, int capC)
{
    int b = blockIdx.x;
    int nB = cnt[0]; if (nB > capB) nB = capB;
    if (b >= nB) return;
    int t = threadIdx.x;
    int base = t * 12;

    float xr[12], av[12];
    {
        const u16* p = XR1 + (size_t)b * 3072 + base;
        uint2 q0 = *reinterpret_cast<const uint2*>(p);
        uint2 q1 = *reinterpret_cast<const uint2*>(p + 4);
        uint2 q2 = *reinterpret_cast<const uint2*>(p + 8);
        u32 w[6] = {q0.x, q0.y, q1.x, q1.y, q2.x, q2.y};
        #pragma unroll
        for (int j = 0; j < 6; ++j) {
            xr[2*j]   = bf2f((u16)(w[j] & 0xFFFF));
            xr[2*j+1] = bf2f((u16)(w[j] >> 16));
        }
        float4 a0 = *reinterpret_cast<const float4*>(att1 + base);
        float4 a1 = *reinterpret_cast<const float4*>(att1 + base + 4);
        float4 a2 = *reinterpret_cast<const float4*>(att1 + base + 8);
        av[0]=a0.x; av[1]=a0.y; av[2]=a0.z; av[3]=a0.w;
        av[4]=a1.x; av[5]=a1.y; av[6]=a1.z; av[7]=a1.w;
        av[8]=a2.x; av[9]=a2.y; av[10]=a2.z; av[11]=a2.w;
    }

    float acc[12];
    #pragma unroll
    for (int j = 0; j < 12; ++j) acc[j] = 0.f;
    float sumex = 0.f;

    int n = deg1[b]; if (n > BINW) n = BINW;
    for (int i = 0; i < n; ++i) {
        int s = e1bin[b * BINW + i];
        int c = mapC[s];
        if (c < 0) c = 0; if (c >= capC) c = capC - 1;
        float xl[12];
        const u16* p = XL1 + (size_t)c * 3072 + base;
        uint2 q0 = *reinterpret_cast<const uint2*>(p);
        uint2 q1 = *reinterpret_cast<const uint2*>(p + 4);
        uint2 q2 = *reinterpret_cast<const uint2*>(p + 8);
        u32 w[6] = {q0.x, q0.y, q1.x, q1.y, q2.x, q2.y};
        #pragma unroll
        for (int j = 0; j < 6; ++j) {
            xl[2*j]   = bf2f((u16)(w[j] & 0xFFFF));
            xl[2*j+1] = bf2f((u16)(w[j] >> 16));
        }
        float pa = 0.f;
        #pragma unroll
        for (int j = 0; j < 12; ++j)
            pa = fmaf(av[j], lrelu(xl[j] + xr[j]), pa);
        #pragma unroll
        for (int off = 32; off > 0; off >>= 1) pa += __shfl_xor(pa, off);
        float ex = expf(pa);
        sumex += ex;
        #pragma unroll
        for (int j = 0; j < 12; ++j) acc[j] = fmaf(ex, xl[j], acc[j]);
    }

    float inv = 1.f / (sumex + 1e-16f);
    u32 o[6];
    #pragma unroll
    for (int j = 0; j < 6; ++j) {
        float v0 = acc[2*j]   * inv + bias1[base + 2*j];
        float v1 = acc[2*j+1] * inv + bias1[base + 2*j+1];
        v0 = v0 > 0.f ? v0 : 0.f;
        v1 = v1 > 0.f ? v1 : 0.f;
        o[j] = (u32)f2bf(v0) | ((u32)f2bf(v1) << 16);
    }
    u16* q = H1bf + (size_t)b * 3072 + base;
    uint2 s0; s0.x = o[0]; s0.y = o[1];
    uint2 s1; s1.x = o[2]; s1.y = o[3];
    uint2 s2; s2.x = o[4]; s2.y = o[5];
    *reinterpret_cast<uint2*>(q)     = s0;
    *reinterpret_cast<uint2*>(q + 4) = s1;
    *reinterpret_cast<uint2*>(q + 8) = s2;
}

// ------------------------------------------------------------------
// Fused layer-2 edge phase: one wave per pathology node (14 blocks x 64).
// XLR2[b][0..767]=XL2', [768..1535]=XR2' (f32, biases included).
// Writes d_out directly.
// ------------------------------------------------------------------
__global__ __launch_bounds__(64)
void k_fused2(const float* __restrict__ XLR2,
              const float* __restrict__ att2, const float* __restrict__ bias2,
              const int* __restrict__ mapB,
              const int* __restrict__ deg2, const int* __restrict__ e2bin,
              float* __restrict__ out, int capB)
{
    int a = blockIdx.x;
    int lane = threadIdx.x;
    int base = lane * 12;

    int bd = mapB[a];
    if (bd < 0) bd = 0; if (bd >= capB) bd = capB - 1;

    float xr[12], av[12];
    {
        const float* p = XLR2 + (size_t)bd * 1536 + 768 + base;
        float4 r0 = *reinterpret_cast<const float4*>(p);
        float4 r1 = *reinterpret_cast<const float4*>(p + 4);
        float4 r2 = *reinterpret_cast<const float4*>(p + 8);
        xr[0]=r0.x; xr[1]=r0.y; xr[2]=r0.z; xr[3]=r0.w;
        xr[4]=r1.x; xr[5]=r1.y; xr[6]=r1.z; xr[7]=r1.w;
        xr[8]=r2.x; xr[9]=r2.y; xr[10]=r2.z; xr[11]=r2.w;
        float4 a0 = *reinterpret_cast<const float4*>(att2 + base);
        float4 a1 = *reinterpret_cast<const float4*>(att2 + base + 4);
        float4 a2 = *reinterpret_cast<const float4*>(att2 + base + 8);
        av[0]=a0.x; av[1]=a0.y; av[2]=a0.z; av[3]=a0.w;
        av[4]=a1.x; av[5]=a1.y; av[6]=a1.z; av[7]=a1.w;
        av[8]=a2.x; av[9]=a2.y; av[10]=a2.z; av[11]=a2.w;
    }

    float acc[12];
    #pragma unroll
    for (int j = 0; j < 12; ++j) acc[j] = 0.f;
    float sumex = 0.f;

    int n = deg2[a]; if (n > BINW) n = BINW;
    for (int i = 0; i < n; ++i) {
        int s = e2bin[a * BINW + i];
        int bs = mapB[s];
        if (bs < 0) bs = 0; if (bs >= capB) bs = capB - 1;
        float xl[12];
        const float* p = XLR2 + (size_t)bs * 1536 + base;
        float4 r0 = *reinterpret_cast<const float4*>(p);
        float4 r1 = *reinterpret_cast<const float4*>(p + 4);
        float4 r2 = *reinterpret_cast<const float4*>(p + 8);
        xl[0]=r0.x; xl[1]=r0.y; xl[2]=r0.z; xl[3]=r0.w;
        xl[4]=r1.x; xl[5]=r1.y; xl[6]=r1.z; xl[7]=r1.w;
        xl[8]=r2.x; xl[9]=r2.y; xl[10]=r2.z; xl[11]=r2.w;
        float pa = 0.f;
        #pragma unroll
        for (int j = 0; j < 12; ++j)
            pa = fmaf(av[j], lrelu(xl[j] + xr[j]), pa);
        #pragma unroll
        for (int off = 32; off > 0; off >>= 1) pa += __shfl_xor(pa, off);
        float ex = expf(pa);
        sumex += ex;
        #pragma unroll
        for (int j = 0; j < 12; ++j) acc[j] = fmaf(ex, xl[j], acc[j]);
    }

    float inv = 1.f / (sumex + 1e-16f);
    float* q = out + (size_t)a * 768 + base;
    #pragma unroll
    for (int j = 0; j < 12; ++j)
        q[j] = acc[j] * inv + bias2[base + j];
}

// ------------------------------------------------------------------
// Host side
// ------------------------------------------------------------------
struct Lay {
    size_t mapB, mapC;
    size_t zbase, zbytes;
    size_t cnt, deg2, deg1, XLR2;
    size_t listB, listC, e1bin, e2bin;
    size_t Wl1t, Wr1t, W2t, XL1, XR1, H1bf;
    size_t total;
};

static Lay makeLayout(int Nn, int cB, int cC)
{
    Lay L{};
    size_t off = 0;
    auto take = [&](size_t bytes) { size_t o = (off + 255) & ~(size_t)255; off = o + bytes; return o; };
    L.mapB = take((size_t)2 * Nn * 4);
    L.mapC = L.mapB + (size_t)Nn * 4;
    // contiguous zero region
    size_t zo = 0;
    size_t cntO  = zo; zo += 64;
    size_t deg2O = zo; zo += 64 * 4;
    size_t deg1O = zo; zo += (size_t)cB * 4;
    zo = (zo + 255) & ~(size_t)255;
    size_t xlr2O = zo; zo += (size_t)cB * 1536 * 4;
    L.zbase = take(zo); L.zbytes = zo;
    L.cnt  = L.zbase + cntO;
    L.deg2 = L.zbase + deg2O;
    L.deg1 = L.zbase + deg1O;
    L.XLR2 = L.zbase + xlr2O;
    L.listB = take((size_t)cB * 4);
    L.listC = take((size_t)cC * 4);
    L.e1bin = take((size_t)cB * BINW * 4);
    L.e2bin = take((size_t)16 * BINW * 4);
    L.Wl1t = take((size_t)3072 * 768 * 2);
    L.Wr1t = take((size_t)3072 * 768 * 2);
    L.W2t  = take((size_t)1536 * 3072 * 2);
    L.XL1  = take((size_t)cC * 3072 * 2);
    L.XR1  = take((size_t)cB * 3072 * 2);
    L.H1bf = take((size_t)cB * 3072 * 2);
    L.total = off;
    return L;
}

extern "C" void kernel_launch(void* const* d_in, const int* in_sizes, int n_in,
                              void* d_out, int out_size, void* d_ws, size_t ws_size,
                              hipStream_t stream)
{
    const float* x     = (const float*)d_in[0];
    const int*   ei    = (const int*)  d_in[1];
    const float* Wl1   = (const float*)d_in[2];
    const float* bl1   = (const float*)d_in[3];
    const float* Wr1   = (const float*)d_in[4];
    const float* br1   = (const float*)d_in[5];
    const float* att1  = (const float*)d_in[6];
    const float* bias1 = (const float*)d_in[7];
    const float* Wl2   = (const float*)d_in[8];
    const float* bl2   = (const float*)d_in[9];
    const float* Wr2   = (const float*)d_in[10];
    const float* br2   = (const float*)d_in[11];
    const float* att2  = (const float*)d_in[12];
    const float* bias2 = (const float*)d_in[13];
    float* out = (float*)d_out;

    int Nn = in_sizes[0] / 768;
    int E  = in_sizes[1] / 2;
    const int* esrc = ei;
    const int* edst = ei + E;
    int ET = E + Nn;

    // expected actual sizes: B~85, C~620
    static const int tiers[2][2] = { {256, 1024}, {128, 768} };
    int capB = tiers[1][0], capC = tiers[1][1];
    Lay L = makeLayout(Nn, capB, capC);
    for (int t = 0; t < 2; ++t) {
        Lay cand = makeLayout(Nn, tiers[t][0], tiers[t][1]);
        if (cand.total <= ws_size) { capB = tiers[t][0]; capC = tiers[t][1]; L = cand; break; }
    }

    char* ws = (char*)d_ws;
    int*   mapB  = (int*)  (ws + L.mapB);
    int*   mapC  = (int*)  (ws + L.mapC);
    int*   cnt   = (int*)  (ws + L.cnt);
    int*   deg2  = (int*)  (ws + L.deg2);
    int*   deg1  = (int*)  (ws + L.deg1);
    float* XLR2  = (float*)(ws + L.XLR2);
    int*   listB = (int*)  (ws + L.listB);
    int*   listC = (int*)  (ws + L.listC);
    int*   e1bin = (int*)  (ws + L.e1bin);
    int*   e2bin = (int*)  (ws + L.e2bin);
    u16*   Wl1t  = (u16*)  (ws + L.Wl1t);
    u16*   Wr1t  = (u16*)  (ws + L.Wr1t);
    u16*   W2t   = (u16*)  (ws + L.W2t);
    u16*   XL1   = (u16*)  (ws + L.XL1);
    u16*   XR1   = (u16*)  (ws + L.XR1);
    u16*   H1bf  = (u16*)  (ws + L.H1bf);

    hipMemsetAsync(ws + L.mapB, 0xFF, (size_t)2 * Nn * 4, stream);
    hipMemsetAsync(ws + L.zbase, 0, L.zbytes, stream);

    int bgrid = (ET + 255) / 256;
    k_build2<<<bgrid, 256, 0, stream>>>(esrc, edst, E, Nn, mapB, listB, cnt,
                                        deg2, e2bin, capB);
    k_build1<<<bgrid, 256, 0, stream>>>(esrc, edst, E, Nn, mapB, mapC, listC, cnt,
                                        deg1, e1bin, capB, capC);
    k_convW<<<dim3(576, 4), 256, 0, stream>>>(Wl1, Wr1, Wl2, Wr2, Wl1t, Wr1t, W2t);

    // XL1' = bf16(x[listC] @ Wl1 + bl1), XR1' = bf16(x[listB] @ Wr1 + br1)
    k_gemm_bf16<<<dim3(48, capC / 64), 256, 0, stream>>>(
        x, 768, 1, listC, Wl1t, 768, XL1, 3072, 2, bl1, bl1, 4096,
        cnt, 1, capC, 768);
    k_gemm_bf16<<<dim3(48, capB / 64), 256, 0, stream>>>(
        x, 768, 1, listB, Wr1t, 768, XR1, 3072, 2, br1, br1, 4096,
        cnt, 0, capB, 768);

    k_fused1<<<capB, 256, 0, stream>>>(XL1, XR1, att1, bias1, mapC, deg1, e1bin,
                                       H1bf, cnt, capB, capC);

    // [XL2'|XR2'] = H1bf @ [Wl2|Wr2] + [bl2|br2]  (f32 atomic, K-split 4)
    k_gemm_bf16<<<dim3(24, capB / 64, 4), 256, 0, stream>>>(
        H1bf, 3072, 0, nullptr, W2t, 3072, XLR2, 1536, 1, bl2, br2, 768,
        cnt, 0, capB, 768);

    k_fused2<<<N_PATH, 64, 0, stream>>>(XLR2, att2, bias2, mapB, deg2, e2bin,
                                        out, capB);
}

// Round 4
// 80.603 us; speedup vs baseline: 3.2006x; 1.3769x over previous
//
#include <hip/hip_runtime.h>
#include <cstdint>
#include <cstddef>

#define N_PATH 14
#define NEG_SLOPE 0.2f
#define BINW 128

using u16 = unsigned short;
using u32 = unsigned int;
typedef __attribute__((ext_vector_type(4))) float f32x4;
typedef __attribute__((ext_vector_type(8))) short bf16x8;

__device__ __forceinline__ float lrelu(float v) { return v > 0.f ? v : NEG_SLOPE * v; }
__device__ __forceinline__ u16 f2bf(float f) {
    union { float f; u32 u; } c; c.f = f;
    return (u16)((c.u + 0x7FFFu + ((c.u >> 16) & 1u)) >> 16);
}
__device__ __forceinline__ float bf2f(u16 v) {
    union { u32 u; float f; } c; c.u = ((u32)v) << 16; return c.f;
}

// ------------------------------------------------------------------
// Init: mapB/mapC = -1, zero region (cnt, deg2, deg1, XLR2)
// ------------------------------------------------------------------
__global__ void k_init(int* __restrict__ mapBC, int nMap,
                       u32* __restrict__ z, int nZ)
{
    int stride = gridDim.x * blockDim.x;
    int i0 = blockIdx.x * blockDim.x + threadIdx.x;
    for (int i = i0; i < nMap; i += stride) mapBC[i] = -1;
    for (int i = i0; i < nZ; i += stride) z[i] = 0;
}

// ------------------------------------------------------------------
// Frontier building. cnt[0]=nB, cnt[1]=nC
// ------------------------------------------------------------------
__global__ void k_build2(const int* __restrict__ esrc, const int* __restrict__ edst,
                         int E, int Nn,
                         int* __restrict__ mapB, int* __restrict__ listB,
                         int* __restrict__ cnt,
                         int* __restrict__ deg2, int* __restrict__ e2bin,
                         int capB)
{
    int e = blockIdx.x * blockDim.x + threadIdx.x;
    int ET = E + Nn;
    if (e >= ET) return;
    int s, d;
    if (e < E) { s = esrc[e]; d = edst[e]; } else { s = e - E; d = s; }
    if (d >= N_PATH) return;
    int slot = atomicAdd(&deg2[d], 1);
    if (slot < BINW) e2bin[d * BINW + slot] = s;
    int old = atomicCAS(&mapB[s], -1, -2);
    if (old == -1) {
        int idx = atomicAdd(&cnt[0], 1);
        if (idx < capB) listB[idx] = s;
        mapB[s] = idx;
    }
}

__global__ void k_build1(const int* __restrict__ esrc, const int* __restrict__ edst,
                         int E, int Nn,
                         const int* __restrict__ mapB,
                         int* __restrict__ mapC, int* __restrict__ listC,
                         int* __restrict__ cnt,
                         int* __restrict__ deg1, int* __restrict__ e1bin,
                         int capB, int capC)
{
    int e = blockIdx.x * blockDim.x + threadIdx.x;
    int ET = E + Nn;
    if (e >= ET) return;
    int s, d;
    if (e < E) { s = esrc[e]; d = edst[e]; } else { s = e - E; d = s; }
    int b = mapB[d];
    if (b < 0 || b >= capB) return;
    int slot = atomicAdd(&deg1[b], 1);
    if (slot < BINW) e1bin[b * BINW + slot] = s;
    int old = atomicCAS(&mapC[s], -1, -2);
    if (old == -1) {
        int idx = atomicAdd(&cnt[1], 1);
        if (idx < capC) listC[idx] = s;
        mapC[s] = idx;
    }
}

// ------------------------------------------------------------------
// Core MFMA GEMM tile: C[r, n] (+)= sum_k A[g(r), k] * W[k, nColOff+n] (+bias)
// A: f32 (aF32=1) or bf16. W: f32 K-major, transposed+converted during
// LDS staging. 64x64 tile, 4 waves, BK=64, 16x16x32 bf16 MFMA, XOR swizzle.
// mode: 1 = f32 atomicAdd, 2 = bf16 store.
// ------------------------------------------------------------------
__device__ __forceinline__
void gemm_tile(const void* __restrict__ A, int lda, int aF32,
               const int* __restrict__ gather,
               const float* __restrict__ W, int ldw, int nColOff,
               const float* __restrict__ bias,
               void* __restrict__ Cout, int ldc, int mode, bool addBias,
               const int* __restrict__ cnt, int cntIdx, int capM,
               int bx, int by, int k0, int kchunk,
               u16* __restrict__ As, u16* __restrict__ Bs)
{
    int M = cnt[cntIdx]; if (M > capM) M = capM;
    int m0 = by * 64;
    if (m0 >= M) return;
    int n0 = bx * 64;
    int t = threadIdx.x;
    int lane = t & 63, wave = t >> 6;
    int wr = wave >> 1, wc = wave & 1;
    int lrow = lane & 15, lhi = lane >> 4;

    // A staging coords: thread covers rows t>>3 and 32+(t>>3), 8 k each
    int chunk = t & 7;
    int rowp[2], aRow[2], wIdx[2];
    #pragma unroll
    for (int p = 0; p < 2; ++p) {
        rowp[p] = p * 32 + (t >> 3);
        int ar = m0 + rowp[p]; if (ar >= M) ar = M - 1;
        aRow[p] = gather ? gather[ar] : ar;
        wIdx[p] = rowp[p] * 64 + ((chunk ^ (rowp[p] & 7)) << 3);
    }
    // B staging coords: thread covers k = p*16 + (t>>4), n = (t&15)*4 .. +3
    int bk = t >> 4;
    int bn = (t & 15) << 2;

    int aIdx[2][2], bIdx[2][2];
    #pragma unroll
    for (int mi = 0; mi < 2; ++mi)
        #pragma unroll
        for (int ks = 0; ks < 2; ++ks) {
            int ra = wr * 32 + mi * 16 + lrow;
            aIdx[mi][ks] = ra * 64 + ((((ks << 2) | lhi) ^ (ra & 7)) << 3);
            int rb = wc * 32 + mi * 16 + lrow;
            bIdx[mi][ks] = rb * 64 + ((((ks << 2) | lhi) ^ (rb & 7)) << 3);
        }

    f32x4 acc[2][2];
    #pragma unroll
    for (int i = 0; i < 2; ++i)
        #pragma unroll
        for (int j = 0; j < 2; ++j)
            acc[i][j] = (f32x4){0.f, 0.f, 0.f, 0.f};

    for (int kt = 0; kt < kchunk; kt += 64) {
        int kb = k0 + kt;
        // stage A
        #pragma unroll
        for (int p = 0; p < 2; ++p) {
            uint4 av;
            if (aF32) {
                const float* ap = (const float*)A + (size_t)aRow[p] * lda + kb + chunk * 8;
                float4 f0 = *reinterpret_cast<const float4*>(ap);
                float4 f1 = *reinterpret_cast<const float4*>(ap + 4);
                av.x = (u32)f2bf(f0.x) | ((u32)f2bf(f0.y) << 16);
                av.y = (u32)f2bf(f0.z) | ((u32)f2bf(f0.w) << 16);
                av.z = (u32)f2bf(f1.x) | ((u32)f2bf(f1.y) << 16);
                av.w = (u32)f2bf(f1.z) | ((u32)f2bf(f1.w) << 16);
            } else {
                av = *reinterpret_cast<const uint4*>((const u16*)A + (size_t)aRow[p] * lda + kb + chunk * 8);
            }
            *reinterpret_cast<uint4*>(&As[wIdx[p]]) = av;
        }
        // stage B: transpose+convert from f32 W[k][n]
        #pragma unroll
        for (int p = 0; p < 4; ++p) {
            int kk = p * 16 + bk;
            const float* wp = W + (size_t)(kb + kk) * ldw + nColOff + n0 + bn;
            float4 wv = *reinterpret_cast<const float4*>(wp);
            float wa[4] = {wv.x, wv.y, wv.z, wv.w};
            #pragma unroll
            for (int j = 0; j < 4; ++j) {
                int n = bn + j;
                int pc = (kk & 7) | ((((kk >> 3) & 7) ^ (n & 7)) << 3);
                Bs[n * 64 + pc] = f2bf(wa[j]);
            }
        }
        __syncthreads();
        #pragma unroll
        for (int ks = 0; ks < 2; ++ks) {
            bf16x8 a0 = *reinterpret_cast<const bf16x8*>(&As[aIdx[0][ks]]);
            bf16x8 a1 = *reinterpret_cast<const bf16x8*>(&As[aIdx[1][ks]]);
            bf16x8 b0 = *reinterpret_cast<const bf16x8*>(&Bs[bIdx[0][ks]]);
            bf16x8 b1 = *reinterpret_cast<const bf16x8*>(&Bs[bIdx[1][ks]]);
            acc[0][0] = __builtin_amdgcn_mfma_f32_16x16x32_bf16(a0, b0, acc[0][0], 0, 0, 0);
            acc[0][1] = __builtin_amdgcn_mfma_f32_16x16x32_bf16(a0, b1, acc[0][1], 0, 0, 0);
            acc[1][0] = __builtin_amdgcn_mfma_f32_16x16x32_bf16(a1, b0, acc[1][0], 0, 0, 0);
            acc[1][1] = __builtin_amdgcn_mfma_f32_16x16x32_bf16(a1, b1, acc[1][1], 0, 0, 0);
        }
        __syncthreads();
    }

    #pragma unroll
    for (int mi = 0; mi < 2; ++mi)
        #pragma unroll
        for (int ni = 0; ni < 2; ++ni) {
            int gc = n0 + wc * 32 + ni * 16 + lrow;
            float bv = addBias ? bias[gc] : 0.f;
            #pragma unroll
            for (int j = 0; j < 4; ++j) {
                int gr = m0 + wr * 32 + mi * 16 + lhi * 4 + j;
                if (gr < M) {
                    float v = acc[mi][ni][j] + bv;
                    if (mode == 2) ((u16*)Cout)[(size_t)gr * ldc + gc] = f2bf(v);
                    else           atomicAdd(&((float*)Cout)[(size_t)gr * ldc + gc], v);
                }
            }
        }
}

// Layer-1: XL1' = bf16(x[listC]@Wl1 + bl1), XR1' = bf16(x[listB]@Wr1 + br1)
__global__ __launch_bounds__(256)
void k_gemm1(const float* __restrict__ x,
             const int* __restrict__ listC, const int* __restrict__ listB,
             const float* __restrict__ Wl1, const float* __restrict__ Wr1,
             const float* __restrict__ bl1, const float* __restrict__ br1,
             u16* __restrict__ XL1, u16* __restrict__ XR1,
             const int* __restrict__ cnt, int capC, int capB)
{
    __shared__ __align__(16) u16 As[64 * 64];
    __shared__ __align__(16) u16 Bs[64 * 64];
    int partA = 48 * (capC / 64);
    int bid = blockIdx.x;
    if (bid < partA) {
        gemm_tile(x, 768, 1, listC, Wl1, 3072, 0, bl1, XL1, 3072, 2, true,
                  cnt, 1, capC, bid % 48, bid / 48, 0, 768, As, Bs);
    } else {
        bid -= partA;
        gemm_tile(x, 768, 1, listB, Wr1, 3072, 0, br1, XR1, 3072, 2, true,
                  cnt, 0, capB, bid % 48, bid / 48, 0, 768, As, Bs);
    }
}

// Layer-2: [XL2'|XR2'] = H1bf @ [Wl2|Wr2] + [bl2|br2], f32 atomic, K-split 8
__global__ __launch_bounds__(256)
void k_gemm2(const u16* __restrict__ H1bf,
             const float* __restrict__ Wl2, const float* __restrict__ Wr2,
             const float* __restrict__ bl2, const float* __restrict__ br2,
             float* __restrict__ XLR2,
             const int* __restrict__ cnt, int capB)
{
    __shared__ __align__(16) u16 As[64 * 64];
    __shared__ __align__(16) u16 Bs[64 * 64];
    int bx = blockIdx.x;                 // 0..23 (global col tile over 1536)
    bool hi = bx >= 12;
    const float* W    = hi ? Wr2 : Wl2;
    const float* bias = hi ? br2 - 768 : bl2;
    int nColOff = hi ? -768 : 0;
    gemm_tile(H1bf, 3072, 0, nullptr, W, 768, nColOff, bias, XLR2, 1536, 1,
              blockIdx.z == 0, cnt, 0, capB, bx, blockIdx.y,
              blockIdx.z * 384, 384, As, Bs);
}

// ------------------------------------------------------------------
// Fused layer-1 edge phase: one block per B node, wave h owns head h.
// LDS-precomputed edge indices + register prefetch of next source row.
// ------------------------------------------------------------------
__global__ __launch_bounds__(256)
void k_fused1(const u16* __restrict__ XL1, const u16* __restrict__ XR1,
              const float* __restrict__ att1, const float* __restrict__ bias1,
              const int* __restrict__ mapC,
              const int* __restrict__ deg1, const int* __restrict__ e1bin,
              u16* __restrict__ H1bf,
              const int* __restrict__ cnt, int capB, int capC)
{
    __shared__ int sIdx[BINW];
    int b = blockIdx.x;
    int nB = cnt[0]; if (nB > capB) nB = capB;
    if (b >= nB) return;
    int t = threadIdx.x;
    int n = deg1[b]; if (n > BINW) n = BINW;
    if (t < n) {
        int c = mapC[e1bin[b * BINW + t]];
        if (c < 0) c = 0; if (c >= capC) c = capC - 1;
        sIdx[t] = c;
    }
    __syncthreads();

    int base = t * 12;
    float xr[12], av[12];
    {
        const u16* p = XR1 + (size_t)b * 3072 + base;
        uint2 q0 = *reinterpret_cast<const uint2*>(p);
        uint2 q1 = *reinterpret_cast<const uint2*>(p + 4);
        uint2 q2 = *reinterpret_cast<const uint2*>(p + 8);
        u32 w[6] = {q0.x, q0.y, q1.x, q1.y, q2.x, q2.y};
        #pragma unroll
        for (int j = 0; j < 6; ++j) {
            xr[2*j]   = bf2f((u16)(w[j] & 0xFFFF));
            xr[2*j+1] = bf2f((u16)(w[j] >> 16));
        }
        float4 a0 = *reinterpret_cast<const float4*>(att1 + base);
        float4 a1 = *reinterpret_cast<const float4*>(att1 + base + 4);
        float4 a2 = *reinterpret_cast<const float4*>(att1 + base + 8);
        av[0]=a0.x; av[1]=a0.y; av[2]=a0.z; av[3]=a0.w;
        av[4]=a1.x; av[5]=a1.y; av[6]=a1.z; av[7]=a1.w;
        av[8]=a2.x; av[9]=a2.y; av[10]=a2.z; av[11]=a2.w;
    }

    float acc[12];
    #pragma unroll
    for (int j = 0; j < 12; ++j) acc[j] = 0.f;
    float sumex = 0.f;

    uint2 q0, q1, q2;           // prefetched next row
    if (n > 0) {
        const u16* p = XL1 + (size_t)sIdx[0] * 3072 + base;
        q0 = *reinterpret_cast<const uint2*>(p);
        q1 = *reinterpret_cast<const uint2*>(p + 4);
        q2 = *reinterpret_cast<const uint2*>(p + 8);
    }
    for (int i = 0; i < n; ++i) {
        uint2 r0 = q0, r1 = q1, r2 = q2;
        if (i + 1 < n) {
            const u16* p = XL1 + (size_t)sIdx[i + 1] * 3072 + base;
            q0 = *reinterpret_cast<const uint2*>(p);
            q1 = *reinterpret_cast<const uint2*>(p + 4);
            q2 = *reinterpret_cast<const uint2*>(p + 8);
        }
        float xl[12];
        u32 w[6] = {r0.x, r0.y, r1.x, r1.y, r2.x, r2.y};
        #pragma unroll
        for (int j = 0; j < 6; ++j) {
            xl[2*j]   = bf2f((u16)(w[j] & 0xFFFF));
            xl[2*j+1] = bf2f((u16)(w[j] >> 16));
        }
        float pa = 0.f;
        #pragma unroll
        for (int j = 0; j < 12; ++j)
            pa = fmaf(av[j], lrelu(xl[j] + xr[j]), pa);
        #pragma unroll
        for (int off = 32; off > 0; off >>= 1) pa += __shfl_xor(pa, off);
        float ex = expf(pa);
        sumex += ex;
        #pragma unroll
        for (int j = 0; j < 12; ++j) acc[j] = fmaf(ex, xl[j], acc[j]);
    }

    float inv = 1.f / (sumex + 1e-16f);
    u32 o[6];
    #pragma unroll
    for (int j = 0; j < 6; ++j) {
        float v0 = acc[2*j]   * inv + bias1[base + 2*j];
        float v1 = acc[2*j+1] * inv + bias1[base + 2*j+1];
        v0 = v0 > 0.f ? v0 : 0.f;
        v1 = v1 > 0.f ? v1 : 0.f;
        o[j] = (u32)f2bf(v0) | ((u32)f2bf(v1) << 16);
    }
    u16* q = H1bf + (size_t)b * 3072 + base;
    uint2 s0; s0.x = o[0]; s0.y = o[1];
    uint2 s1; s1.x = o[2]; s1.y = o[3];
    uint2 s2; s2.x = o[4]; s2.y = o[5];
    *reinterpret_cast<uint2*>(q)     = s0;
    *reinterpret_cast<uint2*>(q + 4) = s1;
    *reinterpret_cast<uint2*>(q + 8) = s2;
}

// ------------------------------------------------------------------
// Fused layer-2 edge phase: one block per pathology node, 4 waves split
// the edges, LDS combine. Writes d_out directly.
// ------------------------------------------------------------------
__global__ __launch_bounds__(256)
void k_fused2(const float* __restrict__ XLR2,
              const float* __restrict__ att2, const float* __restrict__ bias2,
              const int* __restrict__ mapB,
              const int* __restrict__ deg2, const int* __restrict__ e2bin,
              float* __restrict__ out, int capB)
{
    __shared__ int sIdx[BINW];
    __shared__ float sAcc[4][768];
    __shared__ float sSum[4];
    int a = blockIdx.x;
    int t = threadIdx.x;
    int wv = t >> 6, lane = t & 63;
    int n = deg2[a]; if (n > BINW) n = BINW;
    if (t < n) {
        int bs = mapB[e2bin[a * BINW + t]];
        if (bs < 0) bs = 0; if (bs >= capB) bs = capB - 1;
        sIdx[t] = bs;
    }
    __syncthreads();

    int base = lane * 12;
    int bd = mapB[a];
    if (bd < 0) bd = 0; if (bd >= capB) bd = capB - 1;

    float xr[12], av[12];
    {
        const float* p = XLR2 + (size_t)bd * 1536 + 768 + base;
        float4 r0 = *reinterpret_cast<const float4*>(p);
        float4 r1 = *reinterpret_cast<const float4*>(p + 4);
        float4 r2 = *reinterpret_cast<const float4*>(p + 8);
        xr[0]=r0.x; xr[1]=r0.y; xr[2]=r0.z; xr[3]=r0.w;
        xr[4]=r1.x; xr[5]=r1.y; xr[6]=r1.z; xr[7]=r1.w;
        xr[8]=r2.x; xr[9]=r2.y; xr[10]=r2.z; xr[11]=r2.w;
        float4 a0 = *reinterpret_cast<const float4*>(att2 + base);
        float4 a1 = *reinterpret_cast<const float4*>(att2 + base + 4);
        float4 a2 = *reinterpret_cast<const float4*>(att2 + base + 8);
        av[0]=a0.x; av[1]=a0.y; av[2]=a0.z; av[3]=a0.w;
        av[4]=a1.x; av[5]=a1.y; av[6]=a1.z; av[7]=a1.w;
        av[8]=a2.x; av[9]=a2.y; av[10]=a2.z; av[11]=a2.w;
    }

    float acc[12];
    #pragma unroll
    for (int j = 0; j < 12; ++j) acc[j] = 0.f;
    float sumex = 0.f;

    for (int i = wv; i < n; i += 4) {
        int bs = sIdx[i];
        float xl[12];
        const float* p = XLR2 + (size_t)bs * 1536 + base;
        float4 r0 = *reinterpret_cast<const float4*>(p);
        float4 r1 = *reinterpret_cast<const float4*>(p + 4);
        float4 r2 = *reinterpret_cast<const float4*>(p + 8);
        xl[0]=r0.x; xl[1]=r0.y; xl[2]=r0.z; xl[3]=r0.w;
        xl[4]=r1.x; xl[5]=r1.y; xl[6]=r1.z; xl[7]=r1.w;
        xl[8]=r2.x; xl[9]=r2.y; xl[10]=r2.z; xl[11]=r2.w;
        float pa = 0.f;
        #pragma unroll
        for (int j = 0; j < 12; ++j)
            pa = fmaf(av[j], lrelu(xl[j] + xr[j]), pa);
        #pragma unroll
        for (int off = 32; off > 0; off >>= 1) pa += __shfl_xor(pa, off);
        float ex = expf(pa);
        sumex += ex;
        #pragma unroll
        for (int j = 0; j < 12; ++j) acc[j] = fmaf(ex, xl[j], acc[j]);
    }

    if (lane == 0) sSum[wv] = sumex;
    #pragma unroll
    for (int j = 0; j < 12; ++j) sAcc[wv][base + j] = acc[j];
    __syncthreads();

    float tot = sSum[0] + sSum[1] + sSum[2] + sSum[3];
    float inv = 1.f / (tot + 1e-16f);
    for (int c = t; c < 768; c += 256) {
        float s = sAcc[0][c] + sAcc[1][c] + sAcc[2][c] + sAcc[3][c];
        out[(size_t)a * 768 + c] = s * inv + bias2[c];
    }
}

// ------------------------------------------------------------------
// Host side
// ------------------------------------------------------------------
struct Lay {
    size_t mapB, mapC;
    size_t zbase, zbytes;
    size_t cnt, deg2, deg1, XLR2;
    size_t listB, listC, e1bin, e2bin;
    size_t XL1, XR1, H1bf;
    size_t total;
};

static Lay makeLayout(int Nn, int cB, int cC)
{
    Lay L{};
    size_t off = 0;
    auto take = [&](size_t bytes) { size_t o = (off + 255) & ~(size_t)255; off = o + bytes; return o; };
    L.mapB = take((size_t)2 * Nn * 4);
    L.mapC = L.mapB + (size_t)Nn * 4;
    size_t zo = 0;
    size_t cntO  = zo; zo += 64;
    size_t deg2O = zo; zo += 64 * 4;
    size_t deg1O = zo; zo += (size_t)cB * 4;
    zo = (zo + 255) & ~(size_t)255;
    size_t xlr2O = zo; zo += (size_t)cB * 1536 * 4;
    L.zbase = take(zo); L.zbytes = zo;
    L.cnt  = L.zbase + cntO;
    L.deg2 = L.zbase + deg2O;
    L.deg1 = L.zbase + deg1O;
    L.XLR2 = L.zbase + xlr2O;
    L.listB = take((size_t)cB * 4);
    L.listC = take((size_t)cC * 4);
    L.e1bin = take((size_t)cB * BINW * 4);
    L.e2bin = take((size_t)16 * BINW * 4);
    L.XL1  = take((size_t)cC * 3072 * 2);
    L.XR1  = take((size_t)cB * 3072 * 2);
    L.H1bf = take((size_t)cB * 3072 * 2);
    L.total = off;
    return L;
}

extern "C" void kernel_launch(void* const* d_in, const int* in_sizes, int n_in,
                              void* d_out, int out_size, void* d_ws, size_t ws_size,
                              hipStream_t stream)
{
    const float* x     = (const float*)d_in[0];
    const int*   ei    = (const int*)  d_in[1];
    const float* Wl1   = (const float*)d_in[2];
    const float* bl1   = (const float*)d_in[3];
    const float* Wr1   = (const float*)d_in[4];
    const float* br1   = (const float*)d_in[5];
    const float* att1  = (const float*)d_in[6];
    const float* bias1 = (const float*)d_in[7];
    const float* Wl2   = (const float*)d_in[8];
    const float* bl2   = (const float*)d_in[9];
    const float* Wr2   = (const float*)d_in[10];
    const float* br2   = (const float*)d_in[11];
    const float* att2  = (const float*)d_in[12];
    const float* bias2 = (const float*)d_in[13];
    float* out = (float*)d_out;

    int Nn = in_sizes[0] / 768;
    int E  = in_sizes[1] / 2;
    const int* esrc = ei;
    const int* edst = ei + E;
    int ET = E + Nn;

    // expected actual sizes: B~85, C~550
    static const int tiers[2][2] = { {256, 1024}, {128, 768} };
    int capB = tiers[1][0], capC = tiers[1][1];
    Lay L = makeLayout(Nn, capB, capC);
    for (int t = 0; t < 2; ++t) {
        Lay cand = makeLayout(Nn, tiers[t][0], tiers[t][1]);
        if (cand.total <= ws_size) { capB = tiers[t][0]; capC = tiers[t][1]; L = cand; break; }
    }

    char* ws = (char*)d_ws;
    int*   mapB  = (int*)  (ws + L.mapB);
    int*   mapC  = (int*)  (ws + L.mapC);
    int*   cnt   = (int*)  (ws + L.cnt);
    int*   deg2  = (int*)  (ws + L.deg2);
    int*   deg1  = (int*)  (ws + L.deg1);
    float* XLR2  = (float*)(ws + L.XLR2);
    int*   listB = (int*)  (ws + L.listB);
    int*   listC = (int*)  (ws + L.listC);
    int*   e1bin = (int*)  (ws + L.e1bin);
    int*   e2bin = (int*)  (ws + L.e2bin);
    u16*   XL1   = (u16*)  (ws + L.XL1);
    u16*   XR1   = (u16*)  (ws + L.XR1);
    u16*   H1bf  = (u16*)  (ws + L.H1bf);

    k_init<<<512, 256, 0, stream>>>((int*)(ws + L.mapB), 2 * Nn,
                                    (u32*)(ws + L.zbase), (int)(L.zbytes / 4));

    int bgrid = (ET + 255) / 256;
    k_build2<<<bgrid, 256, 0, stream>>>(esrc, edst, E, Nn, mapB, listB, cnt,
                                        deg2, e2bin, capB);
    k_build1<<<bgrid, 256, 0, stream>>>(esrc, edst, E, Nn, mapB, mapC, listC, cnt,
                                        deg1, e1bin, capB, capC);

    int g1 = 48 * (capC / 64) + 48 * (capB / 64);
    k_gemm1<<<g1, 256, 0, stream>>>(x, listC, listB, Wl1, Wr1, bl1, br1,
                                    XL1, XR1, cnt, capC, capB);

    k_fused1<<<capB, 256, 0, stream>>>(XL1, XR1, att1, bias1, mapC, deg1, e1bin,
                                       H1bf, cnt, capB, capC);

    k_gemm2<<<dim3(24, capB / 64, 8), 256, 0, stream>>>(H1bf, Wl2, Wr2, bl2, br2,
                                                        XLR2, cnt, capB);

    k_fused2<<<N_PATH, 256, 0, stream>>>(XLR2, att2, bias2, mapB, deg2, e2bin,
                                         out, capB);
}